// Round 3
// baseline (676.142 us; speedup 1.0000x reference)
//
#include <hip/hip_runtime.h>
#include <math.h>

// ---------------------------------------------------------------------------
// HierarchicalVQEncoder forward.
//
// Eval mode: assign = hard one-hot (soft terms cancel), so out[b,t] depends
// ONLY on (idx1[b], idx2[b,t]) -> 8*32=256-row table + gather.
//
// idx2 = argmax_k [ r . H_all[i1][:,k] + f_all[i1][k] ],
//   r = relu(ln(x@Wl1^T+bl1))   (argmax invariant to positive scaling;
//   H,f fold Wl2,Wtb,btb,cb2; computed for ALL 8 i1 to break dependency)
//
// 3-kernel DAG:
//   A: x partial stats | tiled transposes (Wl1,Wg1,Wg2,Wp,Wf,Wfb) | fold H_all
//   B: global encoder -> idx1 (16 blocks) | output table (256 blocks)
//   C: main GEMM + LN + scores + argmax + table gather
//      v4: 8x16 thread tile (0.75 B LDS per FMA vs 1.0 at 8x8 -> LDS-return
//      no longer the critical pipe), TM=128, 256 blocks (1/CU, 4 waves),
//      KB=16 double-buffer (48KB), one barrier per K-tile, x-tile XOR chunk
//      swizzle (both-sides: pre-swizzled global source + swizzled read) to
//      kill the 4-way bank conflict from 512B row spacing.
//
// Precision: big GEMM fp32, all folding math fp64.
// ---------------------------------------------------------------------------

#define TM 128
#define KB 16

typedef __attribute__((address_space(3))) void lds_void_t;
typedef const __attribute__((address_space(1))) void glb_void_t;

__device__ __forceinline__ void async_copy16(const float* g, float* l){
  __builtin_amdgcn_global_load_lds((glb_void_t*)g, (lds_void_t*)l, 16, 0, 0);
}

__device__ __forceinline__ double blk_sum_256(double v, double* red){
  const int tid = threadIdx.x;
  red[tid] = v; __syncthreads();
  #pragma unroll
  for(int s=128; s>0; s>>=1){ if(tid < s) red[tid] += red[tid+s]; __syncthreads(); }
  const double r = red[0]; __syncthreads();
  return r;
}

// ---- tiled 64x64 transpose helper (coalesced in AND out) ----------------
__device__ __forceinline__ void tile_transpose(
    const float* __restrict__ src, float* __restrict__ dst,
    int M, int N, int tile_id, float (*tile)[65]){
  const int tpr = N >> 6;
  const int r0 = (tile_id / tpr) << 6;
  const int c0 = (tile_id % tpr) << 6;
  const int t = threadIdx.x;
  {
    const int i = t >> 4, j4 = (t & 15) << 2;
    #pragma unroll
    for(int q=0;q<4;q++){
      const int row = i + (q<<4);
      const float4 v = *(const float4*)&src[(size_t)(r0+row)*N + c0 + j4];
      tile[row][j4+0]=v.x; tile[row][j4+1]=v.y; tile[row][j4+2]=v.z; tile[row][j4+3]=v.w;
    }
  }
  __syncthreads();
  {
    const int j = t >> 4, i4 = (t & 15) << 2;
    #pragma unroll
    for(int q=0;q<4;q++){
      const int col = j + (q<<4);
      float4 o;
      o.x = tile[i4+0][col]; o.y = tile[i4+1][col];
      o.z = tile[i4+2][col]; o.w = tile[i4+3][col];
      *(float4*)&dst[(size_t)(c0+col)*M + r0 + i4] = o;
    }
  }
}

// ========================= Kernel A (488 blocks) =========================
union SmemA {
  float tile[64][65];
  struct { double Wcs[64][33]; double bcs[64]; double cbd[32][64]; double nrm[32]; } fold;
};

__global__ __launch_bounds__(256) void hvq_A(
    const float* __restrict__ x,
    const float* __restrict__ Wl1, const float* __restrict__ Wg1,
    const float* __restrict__ Wf,  const float* __restrict__ Wfb,
    const float* __restrict__ Wg2, const float* __restrict__ Wp,
    const float* __restrict__ Wtb, const float* __restrict__ Wl2,
    const float* __restrict__ bl2, const float* __restrict__ btb,
    const float* __restrict__ cb2,
    double* __restrict__ psum, double* __restrict__ psumsq,
    float* __restrict__ Wl1T, float* __restrict__ Wg1T,
    float* __restrict__ WfT,  float* __restrict__ WfbT,
    float* __restrict__ Wg2T, float* __restrict__ WpT,
    float* __restrict__ H_all, float* __restrict__ f_all){
  __shared__ SmemA sm;
  const int blk = blockIdx.x;
  const int tid = threadIdx.x;

  if(blk < 256){
    const int tc = blk & 15, b = blk >> 4;
    const int d4 = tid * 4;
    const float* xp = x + ((size_t)(b*2048 + tc*128))*1024 + d4;
    double s0=0,s1=0,s2=0,s3=0, q0=0,q1=0,q2=0,q3=0;
    for(int t=0;t<128;t++){
      const float4 v = *(const float4*)&xp[(size_t)t*1024];
      s0 += v.x; q0 += (double)v.x*v.x;
      s1 += v.y; q1 += (double)v.y*v.y;
      s2 += v.z; q2 += (double)v.z*v.z;
      s3 += v.w; q3 += (double)v.w*v.w;
    }
    const size_t o = ((size_t)(b*16+tc))*1024 + d4;
    psum[o+0]=s0; psum[o+1]=s1; psum[o+2]=s2; psum[o+3]=s3;
    psumsq[o+0]=q0; psumsq[o+1]=q1; psumsq[o+2]=q2; psumsq[o+3]=q3;
  } else if(blk < 320){
    tile_transpose(Wl1, Wl1T, 256, 1024, blk-256, sm.tile);
  } else if(blk < 384){
    tile_transpose(Wg1, Wg1T, 256, 1024, blk-320, sm.tile);
  } else if(blk < 408){
    tile_transpose(Wf,  WfT,  256, 384,  blk-384, sm.tile);
  } else if(blk < 412){
    tile_transpose(Wfb, WfbT, 256, 64,   blk-408, sm.tile);
  } else if(blk < 420){
    tile_transpose(Wg2, Wg2T, 128, 256,  blk-412, sm.tile);
  } else if(blk < 424){
    tile_transpose(Wp,  WpT,  128, 128,  blk-420, sm.tile);
  } else {
    const int fb = blk - 424;
    const int ng = fb & 7;
    const int i1 = fb >> 3;
    const int tn = tid & 31;
    const int kq = tid >> 5;
    const int n  = ng*32 + tn;

    if(tid < 32){
      const float* cr = cb2 + ((size_t)i1*32 + tid)*64;
      double n2 = 0;
      for(int c=0;c<64;c++){ const double v=(double)cr[c]; n2 += v*v; }
      sm.fold.nrm[tid] = fmax(sqrt(n2), 1e-12);
    }
    __syncthreads();
    for(int i=tid;i<2048;i+=256){
      const int k = i >> 6, c = i & 63;
      sm.fold.cbd[k][c] = (double)cb2[((size_t)i1*32+k)*64 + c] / sm.fold.nrm[k];
    }
    {
      double acc[8] = {0,0,0,0,0,0,0,0};
      const float* wt = Wtb + (size_t)(kq*8)*256;
      for(int j=0;j<256;j++){
        const double wl = (double)Wl2[(size_t)j*256 + n];
        #pragma unroll
        for(int cc=0;cc<8;cc++) acc[cc] += (double)wt[cc*256 + j] * wl;
      }
      #pragma unroll
      for(int cc=0;cc<8;cc++) sm.fold.Wcs[kq*8+cc][tn] = acc[cc];
    }
    if(tid < 64){
      const float* wt = Wtb + (size_t)tid*256;
      double a = 0;
      for(int j=0;j<256;j++) a += (double)wt[j]*(double)bl2[j];
      sm.fold.bcs[tid] = a + (double)btb[tid];
    }
    __syncthreads();

    double su = 0;
    for(int c=0;c<64;c++) su += sm.fold.Wcs[c][tn];
    su /= 64.0;
    for(int t=0;t<4;t++){
      const int k = kq*4 + t;
      double acc=0, sk=0;
      for(int c=0;c<64;c++){ const double cc = sm.fold.cbd[k][c]; acc += sm.fold.Wcs[c][tn]*cc; sk += cc; }
      H_all[((size_t)i1*256 + n)*32 + k] = (float)(acc - su*sk);
    }
    if(ng == 0 && tid < 32){
      const int k = tid;
      double acc=0, sk=0, sbc=0;
      for(int c=0;c<64;c++){ const double cc = sm.fold.cbd[k][c]; acc += sm.fold.bcs[c]*cc; sk += cc; sbc += sm.fold.bcs[c]; }
      f_all[i1*32 + k] = (float)(acc - (sbc/64.0)*sk);
    }
  }
}

// ========================= Kernel B (272 blocks) =========================
union SmemB {
  struct { float gin[1024]; float sa[256]; float sb[128]; float sh[128];
           double red[256]; double lg[8]; int i1s; } p2;
  struct { float e[64]; float fused[384]; double red[256]; } p4;
};

__global__ __launch_bounds__(256) void hvq_B(
    const double* __restrict__ psum, const double* __restrict__ psumsq,
    const float* __restrict__ Wg1T, const float* __restrict__ bg1,
    const float* __restrict__ Wg2T, const float* __restrict__ bg2,
    const float* __restrict__ WpT,  const float* __restrict__ bp,
    const float* __restrict__ cb1,  const float* __restrict__ cb2,
    const float* __restrict__ WfbT, const float* __restrict__ bfb,
    const float* __restrict__ WfT,  const float* __restrict__ bf,
    int* __restrict__ idx1_g, float* __restrict__ table){
  __shared__ SmemB sm;
  const int tid = threadIdx.x;

  if(blockIdx.x < 16){
    const int b = blockIdx.x;
    for(int i=tid;i<1024;i+=256){
      double s=0, ss=0;
      for(int tc=0;tc<16;tc++){
        const size_t o = ((size_t)(b*16+tc))*1024 + i;
        s += psum[o]; ss += psumsq[o];
      }
      const double mean = s / 2048.0;
      double var = (ss - s*mean) / 2047.0;
      if(var < 0) var = 0;
      sm.p2.gin[i] = (float)(mean + sqrt(var));
    }
    __syncthreads();

    double z = 0;
    {
      #pragma unroll 8
      for(int k=0;k<1024;k++) z += (double)sm.p2.gin[k] * (double)Wg1T[(size_t)k*256 + tid];
      z += (double)bg1[tid];
    }
    const double mz = blk_sum_256(z, sm.p2.red) / 256.0;
    const double dz = z - mz;
    const double vz = blk_sum_256(dz*dz, sm.p2.red) / 256.0;
    double a = dz / sqrt(vz + 1e-5);
    if(a < 0) a = 0;
    sm.p2.sa[tid] = (float)a;
    __syncthreads();

    if(tid < 128){
      double g = 0;
      #pragma unroll 8
      for(int i=0;i<256;i++) g += (double)sm.p2.sa[i]*(double)Wg2T[(size_t)i*128 + tid];
      sm.p2.sb[tid] = (float)(g + (double)bg2[tid]);
    }
    __syncthreads();

    double h = 0;
    if(tid < 128){
      #pragma unroll 8
      for(int i=0;i<128;i++) h += (double)sm.p2.sb[i]*(double)WpT[(size_t)i*128 + tid];
      h += (double)bp[tid];
    }
    const double mh = blk_sum_256(tid<128 ? h : 0.0, sm.p2.red) / 128.0;
    const double dh = (tid<128) ? (h - mh) : 0.0;
    const double vh = blk_sum_256(dh*dh, sm.p2.red) / 128.0;
    const double h1 = dh / sqrt(vh + 1e-5);
    if(tid < 128) sm.p2.sh[tid] = (float)h1;
    const double nh2 = blk_sum_256(tid<128 ? h1*h1 : 0.0, sm.p2.red);
    const double normh = sqrt(nh2);
    __syncthreads();

    if(tid < 8){
      const float* cr = cb1 + tid*128;
      double dsum=0, n2=0;
      for(int i=0;i<128;i++){ const double c=(double)cr[i]; dsum += (double)sm.p2.sh[i]*c; n2 += c*c; }
      sm.p2.lg[tid] = dsum / (fmax(normh,1e-12) * fmax(sqrt(n2),1e-12));
    }
    __syncthreads();
    if(tid == 0){
      int bi=0; double bv=sm.p2.lg[0];
      for(int j=1;j<8;j++) if(sm.p2.lg[j] > bv){ bv=sm.p2.lg[j]; bi=j; }
      idx1_g[b] = bi;
    }
  } else {
    const int row = blockIdx.x - 16;
    const int i1 = row >> 5, k2 = row & 31;
    const int j = tid;
    if(j < 64) sm.p4.e[j] = cb2[((size_t)i1*32 + k2)*64 + j];
    if(j >= 128 && j < 256) sm.p4.fused[256 + (j-128)] = cb1[i1*128 + (j-128)];
    __syncthreads();

    double t = 0;
    {
      #pragma unroll 8
      for(int c=0;c<64;c++) t += (double)sm.p4.e[c]*(double)WfbT[(size_t)c*256 + j];
      t += (double)bfb[j];
    }
    double m = blk_sum_256(t, sm.p4.red) / 256.0;
    double d = t - m;
    double v = blk_sum_256(d*d, sm.p4.red) / 256.0;
    sm.p4.fused[j] = (float)(d / sqrt(v + 1e-5));
    __syncthreads();

    double o = 0;
    {
      #pragma unroll 8
      for(int i=0;i<384;i++) o += (double)sm.p4.fused[i]*(double)WfT[(size_t)i*256 + j];
      o += (double)bf[j];
    }
    m = blk_sum_256(o, sm.p4.red) / 256.0;
    d = o - m;
    v = blk_sum_256(d*d, sm.p4.red) / 256.0;
    double r = d / sqrt(v + 1e-5);
    if(r < 0) r = 0;
    table[(size_t)row*256 + j] = (float)r;
  }
}

// ========================= Kernel C: main (TM=128) =======================
// v4 geometry: 256 threads = 16 tx (16 cols each) x 16 ty (8 rows each).
// Thread tile 8x16 -> per kk: 8 x-floats + 16 w-floats for 128 FMA
// (0.75 B/FMA LDS traffic; 8x8 was 1.0 and LDS-return-bound at ~164us).
// Buffer: W [16][256] 16KB + x [128][16] 8KB = 24KB; dbuf 48KB; 1 block/CU.
// x-tile chunk swizzle: LDS 16B-chunk (row*4 + kc) holds source k-chunk
// kc ^ ((row>>3)&3); read slot = kg ^ (ty&3). Breaks the 4-way bank
// conflict (rows 8 apart = 512B = same banks) while keeping DMA linear.
#define WFLOATS (KB*256)            // 4096
#define BUFSZ   (WFLOATS + TM*KB)   // 6144 floats = 24KB

__global__ __launch_bounds__(256, 1) void hvq_main(
    const float* __restrict__ x, const float* __restrict__ Wl1T,
    const float* __restrict__ bl1, const float* __restrict__ H_all,
    const float* __restrict__ f_all, const int* __restrict__ idx1,
    const float* __restrict__ table, float* __restrict__ out){
  __shared__ float smem[2*BUFSZ];          // 49152 B
  float* rT = smem;                        // [n][36] epilogue, 9216 floats
  int* kstar = (int*)&smem[9216];          // 128 ints, epilogue-only

  const int tid = threadIdx.x;
  const int tx = tid & 15;      // cols tx*16 .. +15
  const int ty = tid >> 4;      // rows ty*8 .. +7
  const int wave = tid >> 6;    // 0..3
  const int lane = tid & 63;
  const int b  = blockIdx.y;
  const int t0 = blockIdx.x * TM;
  const int i1 = idx1[b];

  float acc[8][16];
  #pragma unroll
  for(int j=0;j<8;j++)
    #pragma unroll
    for(int c=0;c<16;c++) acc[j][c] = 0.f;

  float bn[16];
  #pragma unroll
  for(int c=0;c<16;c++) bn[c] = bl1[tx*16 + c];

  // ---- staging sources ----
  // W: 4 insts/wave; inst i covers floats wave*1024 + i*256 (+ lane*4)
  const float* wsrc0 = Wl1T + wave*1024 + lane*4;
  // x: 2 insts/wave; inst i: row = wave*32 + i*16 + (lane>>2),
  //    source k-chunk = (lane&3) ^ (2*i + (lane>>5))   [the XOR swizzle]
  const float* xsrc0 = x + ((size_t)(b*2048 + t0 + wave*32 + (lane>>2)))*1024
                         + (size_t)(((lane&3) ^ (lane>>5)) * 4);
  const float* xsrc1 = x + ((size_t)(b*2048 + t0 + wave*32 + 16 + (lane>>2)))*1024
                         + (size_t)(((lane&3) ^ (2 + (lane>>5))) * 4);

  auto stage = [&](int kt, float* buf) __attribute__((always_inline)) {
    float* wdst = buf + wave*1024;
    const float* ws = wsrc0 + (size_t)kt*WFLOATS;
    #pragma unroll
    for(int i=0;i<4;i++) async_copy16(ws + i*256, wdst + i*256);
    float* xdst0 = buf + WFLOATS + wave*512;
    async_copy16(xsrc0 + kt*KB, xdst0);
    async_copy16(xsrc1 + kt*KB, xdst0 + 256);
  };

  stage(0, smem);

  const int xkey = (ty & 3);           // row>>3 == ty for rows ty*8+j

  for(int kt=0; kt<1024/KB; kt++){
    __syncthreads();   // tile kt landed + compute(kt-1) done -> other buf free
    float* cbuf = smem + (kt&1)*BUFSZ;
    if(kt+1 < 1024/KB) stage(kt+1, smem + ((kt+1)&1)*BUFSZ);

    const float* wsT = cbuf;              // [kk][256]
    const float* xs  = cbuf + WFLOATS;    // [row][16], chunk-swizzled
    #pragma unroll 1
    for(int kg=0; kg<KB/4; kg++){
      float4 xv[8];
      const int slot = (kg ^ xkey) * 4;
      #pragma unroll
      for(int j=0;j<8;j++) xv[j] = *(const float4*)&xs[(ty*8+j)*16 + slot];
      #pragma unroll
      for(int t=0;t<4;t++){
        const int kk = kg*4 + t;
        const float4 w0 = *(const float4*)&wsT[kk*256 + tx*16 + 0];
        const float4 w1 = *(const float4*)&wsT[kk*256 + tx*16 + 4];
        const float4 w2 = *(const float4*)&wsT[kk*256 + tx*16 + 8];
        const float4 w3 = *(const float4*)&wsT[kk*256 + tx*16 + 12];
        #pragma unroll
        for(int j=0;j<8;j++){
          const float xvj = (&xv[j].x)[t];
          acc[j][ 0] = fmaf(xvj, w0.x, acc[j][ 0]);
          acc[j][ 1] = fmaf(xvj, w0.y, acc[j][ 1]);
          acc[j][ 2] = fmaf(xvj, w0.z, acc[j][ 2]);
          acc[j][ 3] = fmaf(xvj, w0.w, acc[j][ 3]);
          acc[j][ 4] = fmaf(xvj, w1.x, acc[j][ 4]);
          acc[j][ 5] = fmaf(xvj, w1.y, acc[j][ 5]);
          acc[j][ 6] = fmaf(xvj, w1.z, acc[j][ 6]);
          acc[j][ 7] = fmaf(xvj, w1.w, acc[j][ 7]);
          acc[j][ 8] = fmaf(xvj, w2.x, acc[j][ 8]);
          acc[j][ 9] = fmaf(xvj, w2.y, acc[j][ 9]);
          acc[j][10] = fmaf(xvj, w2.z, acc[j][10]);
          acc[j][11] = fmaf(xvj, w2.w, acc[j][11]);
          acc[j][12] = fmaf(xvj, w3.x, acc[j][12]);
          acc[j][13] = fmaf(xvj, w3.y, acc[j][13]);
          acc[j][14] = fmaf(xvj, w3.z, acc[j][14]);
          acc[j][15] = fmaf(xvj, w3.w, acc[j][15]);
        }
      }
    }
  }

  // bias + LN(256) per row (reduce across the 16 tx lanes) + ReLU
  #pragma unroll
  for(int j=0;j<8;j++){
    float s = 0.f;
    #pragma unroll
    for(int c=0;c<16;c++){ acc[j][c] += bn[c]; s += acc[j][c]; }
    #pragma unroll
    for(int off=8;off>=1;off>>=1) s += __shfl_xor(s, off);
    const float mean = s * (1.f/256.f);
    float d2 = 0.f;
    #pragma unroll
    for(int c=0;c<16;c++){ const float dv = acc[j][c]-mean; d2 += dv*dv; }
    #pragma unroll
    for(int off=8;off>=1;off>>=1) d2 += __shfl_xor(d2, off);
    const float inv = 1.f / sqrtf(d2*(1.f/256.f) + 1e-5f);
    #pragma unroll
    for(int c=0;c<16;c++) acc[j][c] = fmaxf((acc[j][c]-mean)*inv, 0.f);
  }

  // scores in four 32-row quarters (rT = 32 rows x 256 n, stride 36)
  const int k = tid & 31, mg = tid >> 5;   // mg 0..7
  const float* Hb = H_all + (size_t)i1*256*32 + k;
  const float fk = f_all[i1*32 + k];
  const int quarter = ty >> 2;             // which quarter owns this thread's rows
  const int mm_base = (ty & 3)*8;

  for(int h=0; h<4; h++){
    __syncthreads();                       // prior phase reads done / K-loop done
    if(quarter == h){
      #pragma unroll
      for(int j=0;j<8;j++){
        #pragma unroll
        for(int c=0;c<16;c++){
          rT[(tx*16 + c)*36 + mm_base + j] = acc[j][c];
        }
      }
    }
    __syncthreads();

    float s0=fk, s1=fk, s2=fk, s3=fk;
    #pragma unroll 4
    for(int n=0;n<256;n++){
      const float4 rm = *(const float4*)&rT[n*36 + mg*4];
      const float hv = Hb[(size_t)n*32];
      s0 = fmaf(rm.x, hv, s0);
      s1 = fmaf(rm.y, hv, s1);
      s2 = fmaf(rm.z, hv, s2);
      s3 = fmaf(rm.w, hv, s3);
    }
    float scv[4] = {s0, s1, s2, s3};
    #pragma unroll
    for(int j=0;j<4;j++){
      float best = scv[j]; int bi = k;
      #pragma unroll
      for(int off=16;off>=1;off>>=1){
        const float ov = __shfl_xor(best, off);
        const int   oi = __shfl_xor(bi, off);
        if(ov > best || (ov == best && oi < bi)){ best = ov; bi = oi; }
      }
      if(k == 0) kstar[h*32 + mg*4 + j] = bi;
    }
  }
  __syncthreads();

  float* ob = out + ((size_t)(b*2048 + t0))*256;
  for(int m=0;m<TM;m++){
    const float v = table[((size_t)(i1*32 + kstar[m]))*256 + tid];
    ob[(size_t)m*256 + tid] = v;
  }
}

// ---------------------------------------------------------------------------
extern "C" void kernel_launch(void* const* d_in, const int* in_sizes, int n_in,
                              void* d_out, int out_size, void* d_ws, size_t ws_size,
                              hipStream_t stream){
  const float* x   = (const float*)d_in[0];
  const float* Wg1 = (const float*)d_in[1];
  const float* bg1 = (const float*)d_in[2];
  const float* Wg2 = (const float*)d_in[3];
  const float* bg2 = (const float*)d_in[4];
  const float* Wl1 = (const float*)d_in[5];
  const float* bl1 = (const float*)d_in[6];
  const float* Wl2 = (const float*)d_in[7];
  const float* bl2 = (const float*)d_in[8];
  const float* Wp  = (const float*)d_in[9];
  const float* bp  = (const float*)d_in[10];
  const float* cb1 = (const float*)d_in[11];
  const float* Wtb = (const float*)d_in[12];
  const float* btb = (const float*)d_in[13];
  const float* Wfb = (const float*)d_in[14];
  const float* bfb = (const float*)d_in[15];
  const float* cb2 = (const float*)d_in[16];
  const float* Wf  = (const float*)d_in[17];
  const float* bf  = (const float*)d_in[18];
  float* out = (float*)d_out;

  char* w = (char*)d_ws;
  double* psum   = (double*)w; w += (size_t)16*16*1024*8;   // 2 MB
  double* psumsq = (double*)w; w += (size_t)16*16*1024*8;   // 2 MB
  float*  Wl1T   = (float*)w;  w += (size_t)1024*256*4;     // 1 MB
  float*  Wg1T   = (float*)w;  w += (size_t)1024*256*4;     // 1 MB
  float*  WfT    = (float*)w;  w += (size_t)384*256*4;
  float*  WfbT   = (float*)w;  w += (size_t)64*256*4;
  float*  Wg2T   = (float*)w;  w += (size_t)256*128*4;
  float*  WpT    = (float*)w;  w += (size_t)128*128*4;
  float*  H_all  = (float*)w;  w += (size_t)8*256*32*4;     // 256 KB
  float*  f_all  = (float*)w;  w += (size_t)8*32*4;
  float*  table  = (float*)w;  w += (size_t)256*256*4;      // 256 KB
  int*    idx1   = (int*)w;    w += 64;

  hvq_A<<<488, 256, 0, stream>>>(x, Wl1, Wg1, Wf, Wfb, Wg2, Wp, Wtb, Wl2, bl2, btb, cb2,
                                 psum, psumsq, Wl1T, Wg1T, WfT, WfbT, Wg2T, WpT,
                                 H_all, f_all);
  hvq_B<<<272, 256, 0, stream>>>(psum, psumsq, Wg1T, bg1, Wg2T, bg2, WpT, bp, cb1, cb2,
                                 WfbT, bfb, WfT, bf, idx1, table);
  hvq_main<<<dim3(16,16), 256, 0, stream>>>(x, Wl1T, bl1, H_all, f_all, idx1, table, out);
}

// Round 4
// 655.857 us; speedup vs baseline: 1.0309x; 1.0309x over previous
//
#include <hip/hip_runtime.h>
#include <math.h>

// ---------------------------------------------------------------------------
// HierarchicalVQEncoder forward.
//
// Eval mode: assign = hard one-hot (soft terms cancel), so out[b,t] depends
// ONLY on (idx1[b], idx2[b,t]) -> 8*32=256-row table + gather.
//
// idx2 = argmax_k [ r . H_all[i1][:,k] + f_all[i1][k] ],
//   r = relu(ln(x@Wl1^T+bl1))   (argmax invariant to positive scaling;
//   H,f fold Wl2,Wtb,btb,cb2; computed for ALL 8 i1 to break dependency)
//
// 3-kernel DAG:
//   A: x partial stats | tiled transposes (Wl1,Wg1,Wg2,Wp,Wf,Wfb) | fold H_all
//   B: global encoder -> idx1 (16 blocks) | output table (256 blocks)
//   C: main GEMM + LN + scores + argmax + table gather
//      v5: v4 (8x16 tile, 0.75 B/FMA LDS traffic, TM=128, KB=16 dbuf,
//      one barrier/tile, x chunk-swizzle) + W COLUMN REMAP: thread covers
//      cols q*64 + tx*4 + c (q=0..3) so each W float4 read is 16 lanes at
//      16B stride (2-way, free) instead of 64B stride (8-way conflict that
//      cost v4 ~88us: SQ_LDS_BANK_CONFLICT 54M).
//
// Precision: big GEMM fp32, all folding math fp64.
// ---------------------------------------------------------------------------

#define TM 128
#define KB 16

typedef __attribute__((address_space(3))) void lds_void_t;
typedef const __attribute__((address_space(1))) void glb_void_t;

__device__ __forceinline__ void async_copy16(const float* g, float* l){
  __builtin_amdgcn_global_load_lds((glb_void_t*)g, (lds_void_t*)l, 16, 0, 0);
}

__device__ __forceinline__ double blk_sum_256(double v, double* red){
  const int tid = threadIdx.x;
  red[tid] = v; __syncthreads();
  #pragma unroll
  for(int s=128; s>0; s>>=1){ if(tid < s) red[tid] += red[tid+s]; __syncthreads(); }
  const double r = red[0]; __syncthreads();
  return r;
}

// ---- tiled 64x64 transpose helper (coalesced in AND out) ----------------
__device__ __forceinline__ void tile_transpose(
    const float* __restrict__ src, float* __restrict__ dst,
    int M, int N, int tile_id, float (*tile)[65]){
  const int tpr = N >> 6;
  const int r0 = (tile_id / tpr) << 6;
  const int c0 = (tile_id % tpr) << 6;
  const int t = threadIdx.x;
  {
    const int i = t >> 4, j4 = (t & 15) << 2;
    #pragma unroll
    for(int q=0;q<4;q++){
      const int row = i + (q<<4);
      const float4 v = *(const float4*)&src[(size_t)(r0+row)*N + c0 + j4];
      tile[row][j4+0]=v.x; tile[row][j4+1]=v.y; tile[row][j4+2]=v.z; tile[row][j4+3]=v.w;
    }
  }
  __syncthreads();
  {
    const int j = t >> 4, i4 = (t & 15) << 2;
    #pragma unroll
    for(int q=0;q<4;q++){
      const int col = j + (q<<4);
      float4 o;
      o.x = tile[i4+0][col]; o.y = tile[i4+1][col];
      o.z = tile[i4+2][col]; o.w = tile[i4+3][col];
      *(float4*)&dst[(size_t)(c0+col)*M + r0 + i4] = o;
    }
  }
}

// ========================= Kernel A (488 blocks) =========================
union SmemA {
  float tile[64][65];
  struct { double Wcs[64][33]; double bcs[64]; double cbd[32][64]; double nrm[32]; } fold;
};

__global__ __launch_bounds__(256) void hvq_A(
    const float* __restrict__ x,
    const float* __restrict__ Wl1, const float* __restrict__ Wg1,
    const float* __restrict__ Wf,  const float* __restrict__ Wfb,
    const float* __restrict__ Wg2, const float* __restrict__ Wp,
    const float* __restrict__ Wtb, const float* __restrict__ Wl2,
    const float* __restrict__ bl2, const float* __restrict__ btb,
    const float* __restrict__ cb2,
    double* __restrict__ psum, double* __restrict__ psumsq,
    float* __restrict__ Wl1T, float* __restrict__ Wg1T,
    float* __restrict__ WfT,  float* __restrict__ WfbT,
    float* __restrict__ Wg2T, float* __restrict__ WpT,
    float* __restrict__ H_all, float* __restrict__ f_all){
  __shared__ SmemA sm;
  const int blk = blockIdx.x;
  const int tid = threadIdx.x;

  if(blk < 256){
    const int tc = blk & 15, b = blk >> 4;
    const int d4 = tid * 4;
    const float* xp = x + ((size_t)(b*2048 + tc*128))*1024 + d4;
    double s0=0,s1=0,s2=0,s3=0, q0=0,q1=0,q2=0,q3=0;
    for(int t=0;t<128;t++){
      const float4 v = *(const float4*)&xp[(size_t)t*1024];
      s0 += v.x; q0 += (double)v.x*v.x;
      s1 += v.y; q1 += (double)v.y*v.y;
      s2 += v.z; q2 += (double)v.z*v.z;
      s3 += v.w; q3 += (double)v.w*v.w;
    }
    const size_t o = ((size_t)(b*16+tc))*1024 + d4;
    psum[o+0]=s0; psum[o+1]=s1; psum[o+2]=s2; psum[o+3]=s3;
    psumsq[o+0]=q0; psumsq[o+1]=q1; psumsq[o+2]=q2; psumsq[o+3]=q3;
  } else if(blk < 320){
    tile_transpose(Wl1, Wl1T, 256, 1024, blk-256, sm.tile);
  } else if(blk < 384){
    tile_transpose(Wg1, Wg1T, 256, 1024, blk-320, sm.tile);
  } else if(blk < 408){
    tile_transpose(Wf,  WfT,  256, 384,  blk-384, sm.tile);
  } else if(blk < 412){
    tile_transpose(Wfb, WfbT, 256, 64,   blk-408, sm.tile);
  } else if(blk < 420){
    tile_transpose(Wg2, Wg2T, 128, 256,  blk-412, sm.tile);
  } else if(blk < 424){
    tile_transpose(Wp,  WpT,  128, 128,  blk-420, sm.tile);
  } else {
    const int fb = blk - 424;
    const int ng = fb & 7;
    const int i1 = fb >> 3;
    const int tn = tid & 31;
    const int kq = tid >> 5;
    const int n  = ng*32 + tn;

    if(tid < 32){
      const float* cr = cb2 + ((size_t)i1*32 + tid)*64;
      double n2 = 0;
      for(int c=0;c<64;c++){ const double v=(double)cr[c]; n2 += v*v; }
      sm.fold.nrm[tid] = fmax(sqrt(n2), 1e-12);
    }
    __syncthreads();
    for(int i=tid;i<2048;i+=256){
      const int k = i >> 6, c = i & 63;
      sm.fold.cbd[k][c] = (double)cb2[((size_t)i1*32+k)*64 + c] / sm.fold.nrm[k];
    }
    {
      double acc[8] = {0,0,0,0,0,0,0,0};
      const float* wt = Wtb + (size_t)(kq*8)*256;
      for(int j=0;j<256;j++){
        const double wl = (double)Wl2[(size_t)j*256 + n];
        #pragma unroll
        for(int cc=0;cc<8;cc++) acc[cc] += (double)wt[cc*256 + j] * wl;
      }
      #pragma unroll
      for(int cc=0;cc<8;cc++) sm.fold.Wcs[kq*8+cc][tn] = acc[cc];
    }
    if(tid < 64){
      const float* wt = Wtb + (size_t)tid*256;
      double a = 0;
      for(int j=0;j<256;j++) a += (double)wt[j]*(double)bl2[j];
      sm.fold.bcs[tid] = a + (double)btb[tid];
    }
    __syncthreads();

    double su = 0;
    for(int c=0;c<64;c++) su += sm.fold.Wcs[c][tn];
    su /= 64.0;
    for(int t=0;t<4;t++){
      const int k = kq*4 + t;
      double acc=0, sk=0;
      for(int c=0;c<64;c++){ const double cc = sm.fold.cbd[k][c]; acc += sm.fold.Wcs[c][tn]*cc; sk += cc; }
      H_all[((size_t)i1*256 + n)*32 + k] = (float)(acc - su*sk);
    }
    if(ng == 0 && tid < 32){
      const int k = tid;
      double acc=0, sk=0, sbc=0;
      for(int c=0;c<64;c++){ const double cc = sm.fold.cbd[k][c]; acc += sm.fold.bcs[c]*cc; sk += cc; sbc += sm.fold.bcs[c]; }
      f_all[i1*32 + k] = (float)(acc - (sbc/64.0)*sk);
    }
  }
}

// ========================= Kernel B (272 blocks) =========================
union SmemB {
  struct { float gin[1024]; float sa[256]; float sb[128]; float sh[128];
           double red[256]; double lg[8]; int i1s; } p2;
  struct { float e[64]; float fused[384]; double red[256]; } p4;
};

__global__ __launch_bounds__(256) void hvq_B(
    const double* __restrict__ psum, const double* __restrict__ psumsq,
    const float* __restrict__ Wg1T, const float* __restrict__ bg1,
    const float* __restrict__ Wg2T, const float* __restrict__ bg2,
    const float* __restrict__ WpT,  const float* __restrict__ bp,
    const float* __restrict__ cb1,  const float* __restrict__ cb2,
    const float* __restrict__ WfbT, const float* __restrict__ bfb,
    const float* __restrict__ WfT,  const float* __restrict__ bf,
    int* __restrict__ idx1_g, float* __restrict__ table){
  __shared__ SmemB sm;
  const int tid = threadIdx.x;

  if(blockIdx.x < 16){
    const int b = blockIdx.x;
    for(int i=tid;i<1024;i+=256){
      double s=0, ss=0;
      for(int tc=0;tc<16;tc++){
        const size_t o = ((size_t)(b*16+tc))*1024 + i;
        s += psum[o]; ss += psumsq[o];
      }
      const double mean = s / 2048.0;
      double var = (ss - s*mean) / 2047.0;
      if(var < 0) var = 0;
      sm.p2.gin[i] = (float)(mean + sqrt(var));
    }
    __syncthreads();

    double z = 0;
    {
      #pragma unroll 8
      for(int k=0;k<1024;k++) z += (double)sm.p2.gin[k] * (double)Wg1T[(size_t)k*256 + tid];
      z += (double)bg1[tid];
    }
    const double mz = blk_sum_256(z, sm.p2.red) / 256.0;
    const double dz = z - mz;
    const double vz = blk_sum_256(dz*dz, sm.p2.red) / 256.0;
    double a = dz / sqrt(vz + 1e-5);
    if(a < 0) a = 0;
    sm.p2.sa[tid] = (float)a;
    __syncthreads();

    if(tid < 128){
      double g = 0;
      #pragma unroll 8
      for(int i=0;i<256;i++) g += (double)sm.p2.sa[i]*(double)Wg2T[(size_t)i*128 + tid];
      sm.p2.sb[tid] = (float)(g + (double)bg2[tid]);
    }
    __syncthreads();

    double h = 0;
    if(tid < 128){
      #pragma unroll 8
      for(int i=0;i<128;i++) h += (double)sm.p2.sb[i]*(double)WpT[(size_t)i*128 + tid];
      h += (double)bp[tid];
    }
    const double mh = blk_sum_256(tid<128 ? h : 0.0, sm.p2.red) / 128.0;
    const double dh = (tid<128) ? (h - mh) : 0.0;
    const double vh = blk_sum_256(dh*dh, sm.p2.red) / 128.0;
    const double h1 = dh / sqrt(vh + 1e-5);
    if(tid < 128) sm.p2.sh[tid] = (float)h1;
    const double nh2 = blk_sum_256(tid<128 ? h1*h1 : 0.0, sm.p2.red);
    const double normh = sqrt(nh2);
    __syncthreads();

    if(tid < 8){
      const float* cr = cb1 + tid*128;
      double dsum=0, n2=0;
      for(int i=0;i<128;i++){ const double c=(double)cr[i]; dsum += (double)sm.p2.sh[i]*c; n2 += c*c; }
      sm.p2.lg[tid] = dsum / (fmax(normh,1e-12) * fmax(sqrt(n2),1e-12));
    }
    __syncthreads();
    if(tid == 0){
      int bi=0; double bv=sm.p2.lg[0];
      for(int j=1;j<8;j++) if(sm.p2.lg[j] > bv){ bv=sm.p2.lg[j]; bi=j; }
      idx1_g[b] = bi;
    }
  } else {
    const int row = blockIdx.x - 16;
    const int i1 = row >> 5, k2 = row & 31;
    const int j = tid;
    if(j < 64) sm.p4.e[j] = cb2[((size_t)i1*32 + k2)*64 + j];
    if(j >= 128 && j < 256) sm.p4.fused[256 + (j-128)] = cb1[i1*128 + (j-128)];
    __syncthreads();

    double t = 0;
    {
      #pragma unroll 8
      for(int c=0;c<64;c++) t += (double)sm.p4.e[c]*(double)WfbT[(size_t)c*256 + j];
      t += (double)bfb[j];
    }
    double m = blk_sum_256(t, sm.p4.red) / 256.0;
    double d = t - m;
    double v = blk_sum_256(d*d, sm.p4.red) / 256.0;
    sm.p4.fused[j] = (float)(d / sqrt(v + 1e-5));
    __syncthreads();

    double o = 0;
    {
      #pragma unroll 8
      for(int i=0;i<384;i++) o += (double)sm.p4.fused[i]*(double)WfT[(size_t)i*256 + j];
      o += (double)bf[j];
    }
    m = blk_sum_256(o, sm.p4.red) / 256.0;
    d = o - m;
    v = blk_sum_256(d*d, sm.p4.red) / 256.0;
    double r = d / sqrt(v + 1e-5);
    if(r < 0) r = 0;
    table[(size_t)row*256 + j] = (float)r;
  }
}

// ========================= Kernel C: main (TM=128) =======================
// v5 geometry: 256 threads = 16 tx x 16 ty; thread tile 8 rows x 16 cols
// with cols q*64 + tx*4 + c (q=0..3, c=0..3)  <-- strided quads, so every
// W float4 read is 16 lanes at 16B stride (conflict-free); v4's contiguous
// tx*16 strip was an 8-way conflict (54M conflict cycles).
// Per kk: 8 x-floats + 16 w-floats for 128 FMA = 0.75 B/FMA LDS traffic.
// Buffer: W [16][256] 16KB + x [128][16] 8KB = 24KB; dbuf 48KB; 1 block/CU.
// x-tile chunk swizzle unchanged from v4 (kills 512B-row-spacing conflict).
#define WFLOATS (KB*256)            // 4096
#define BUFSZ   (WFLOATS + TM*KB)   // 6144 floats = 24KB

__global__ __launch_bounds__(256, 1) void hvq_main(
    const float* __restrict__ x, const float* __restrict__ Wl1T,
    const float* __restrict__ bl1, const float* __restrict__ H_all,
    const float* __restrict__ f_all, const int* __restrict__ idx1,
    const float* __restrict__ table, float* __restrict__ out){
  __shared__ float smem[2*BUFSZ];          // 49152 B
  float* rT = smem;                        // [n][36] epilogue, 9216 floats
  int* kstar = (int*)&smem[9216];          // 128 ints, epilogue-only

  const int tid = threadIdx.x;
  const int tx = tid & 15;      // col quads: q*64 + tx*4
  const int ty = tid >> 4;      // rows ty*8 .. +7
  const int wave = tid >> 6;    // 0..3
  const int lane = tid & 63;
  const int b  = blockIdx.y;
  const int t0 = blockIdx.x * TM;
  const int i1 = idx1[b];

  float acc[8][16];
  #pragma unroll
  for(int j=0;j<8;j++)
    #pragma unroll
    for(int c=0;c<16;c++) acc[j][c] = 0.f;

  float bn[16];
  #pragma unroll
  for(int q=0;q<4;q++){
    const float4 bv = *(const float4*)&bl1[q*64 + tx*4];
    bn[q*4+0]=bv.x; bn[q*4+1]=bv.y; bn[q*4+2]=bv.z; bn[q*4+3]=bv.w;
  }

  // ---- staging sources ----
  // W: 4 insts/wave; inst i covers floats wave*1024 + i*256 (+ lane*4)
  const float* wsrc0 = Wl1T + wave*1024 + lane*4;
  // x: 2 insts/wave; inst i: row = wave*32 + i*16 + (lane>>2),
  //    source k-chunk = (lane&3) ^ (2*i + (lane>>5))   [XOR swizzle]
  const float* xsrc0 = x + ((size_t)(b*2048 + t0 + wave*32 + (lane>>2)))*1024
                         + (size_t)(((lane&3) ^ (lane>>5)) * 4);
  const float* xsrc1 = x + ((size_t)(b*2048 + t0 + wave*32 + 16 + (lane>>2)))*1024
                         + (size_t)(((lane&3) ^ (2 + (lane>>5))) * 4);

  auto stage = [&](int kt, float* buf) __attribute__((always_inline)) {
    float* wdst = buf + wave*1024;
    const float* ws = wsrc0 + (size_t)kt*WFLOATS;
    #pragma unroll
    for(int i=0;i<4;i++) async_copy16(ws + i*256, wdst + i*256);
    float* xdst0 = buf + WFLOATS + wave*512;
    async_copy16(xsrc0 + kt*KB, xdst0);
    async_copy16(xsrc1 + kt*KB, xdst0 + 256);
  };

  stage(0, smem);

  const int xkey = (ty & 3);           // row>>3 == ty for rows ty*8+j

  for(int kt=0; kt<1024/KB; kt++){
    __syncthreads();   // tile kt landed + compute(kt-1) done -> other buf free
    float* cbuf = smem + (kt&1)*BUFSZ;
    if(kt+1 < 1024/KB) stage(kt+1, smem + ((kt+1)&1)*BUFSZ);

    const float* wsT = cbuf;              // [kk][256]
    const float* xs  = cbuf + WFLOATS;    // [row][16], chunk-swizzled
    #pragma unroll 1
    for(int kg=0; kg<KB/4; kg++){
      float4 xv[8];
      const int slot = (kg ^ xkey) * 4;
      #pragma unroll
      for(int j=0;j<8;j++) xv[j] = *(const float4*)&xs[(ty*8+j)*16 + slot];
      #pragma unroll
      for(int t=0;t<4;t++){
        const int kk = kg*4 + t;
        const float4 w0 = *(const float4*)&wsT[kk*256 +   0 + tx*4];
        const float4 w1 = *(const float4*)&wsT[kk*256 +  64 + tx*4];
        const float4 w2 = *(const float4*)&wsT[kk*256 + 128 + tx*4];
        const float4 w3 = *(const float4*)&wsT[kk*256 + 192 + tx*4];
        #pragma unroll
        for(int j=0;j<8;j++){
          const float xvj = (&xv[j].x)[t];
          acc[j][ 0] = fmaf(xvj, w0.x, acc[j][ 0]);
          acc[j][ 1] = fmaf(xvj, w0.y, acc[j][ 1]);
          acc[j][ 2] = fmaf(xvj, w0.z, acc[j][ 2]);
          acc[j][ 3] = fmaf(xvj, w0.w, acc[j][ 3]);
          acc[j][ 4] = fmaf(xvj, w1.x, acc[j][ 4]);
          acc[j][ 5] = fmaf(xvj, w1.y, acc[j][ 5]);
          acc[j][ 6] = fmaf(xvj, w1.z, acc[j][ 6]);
          acc[j][ 7] = fmaf(xvj, w1.w, acc[j][ 7]);
          acc[j][ 8] = fmaf(xvj, w2.x, acc[j][ 8]);
          acc[j][ 9] = fmaf(xvj, w2.y, acc[j][ 9]);
          acc[j][10] = fmaf(xvj, w2.z, acc[j][10]);
          acc[j][11] = fmaf(xvj, w2.w, acc[j][11]);
          acc[j][12] = fmaf(xvj, w3.x, acc[j][12]);
          acc[j][13] = fmaf(xvj, w3.y, acc[j][13]);
          acc[j][14] = fmaf(xvj, w3.z, acc[j][14]);
          acc[j][15] = fmaf(xvj, w3.w, acc[j][15]);
        }
      }
    }
  }

  // bias + LN(256) per row (reduce across the 16 tx lanes) + ReLU
  #pragma unroll
  for(int j=0;j<8;j++){
    float s = 0.f;
    #pragma unroll
    for(int c=0;c<16;c++){ acc[j][c] += bn[c]; s += acc[j][c]; }
    #pragma unroll
    for(int off=8;off>=1;off>>=1) s += __shfl_xor(s, off);
    const float mean = s * (1.f/256.f);
    float d2 = 0.f;
    #pragma unroll
    for(int c=0;c<16;c++){ const float dv = acc[j][c]-mean; d2 += dv*dv; }
    #pragma unroll
    for(int off=8;off>=1;off>>=1) d2 += __shfl_xor(d2, off);
    const float inv = 1.f / sqrtf(d2*(1.f/256.f) + 1e-5f);
    #pragma unroll
    for(int c=0;c<16;c++) acc[j][c] = fmaxf((acc[j][c]-mean)*inv, 0.f);
  }

  // scores in four 32-row quarters (rT = 32 rows x 256 n, stride 36)
  const int k = tid & 31, mg = tid >> 5;   // mg 0..7
  const float* Hb = H_all + (size_t)i1*256*32 + k;
  const float fk = f_all[i1*32 + k];
  const int quarter = ty >> 2;             // which quarter owns this thread's rows
  const int mm_base = (ty & 3)*8;

  for(int h=0; h<4; h++){
    __syncthreads();                       // prior phase reads done / K-loop done
    if(quarter == h){
      #pragma unroll
      for(int j=0;j<8;j++){
        #pragma unroll
        for(int q=0;q<4;q++){
          #pragma unroll
          for(int c=0;c<4;c++){
            rT[(q*64 + tx*4 + c)*36 + mm_base + j] = acc[j][q*4+c];
          }
        }
      }
    }
    __syncthreads();

    float s0=fk, s1=fk, s2=fk, s3=fk;
    #pragma unroll 4
    for(int n=0;n<256;n++){
      const float4 rm = *(const float4*)&rT[n*36 + mg*4];
      const float hv = Hb[(size_t)n*32];
      s0 = fmaf(rm.x, hv, s0);
      s1 = fmaf(rm.y, hv, s1);
      s2 = fmaf(rm.z, hv, s2);
      s3 = fmaf(rm.w, hv, s3);
    }
    float scv[4] = {s0, s1, s2, s3};
    #pragma unroll
    for(int j=0;j<4;j++){
      float best = scv[j]; int bi = k;
      #pragma unroll
      for(int off=16;off>=1;off>>=1){
        const float ov = __shfl_xor(best, off);
        const int   oi = __shfl_xor(bi, off);
        if(ov > best || (ov == best && oi < bi)){ best = ov; bi = oi; }
      }
      if(k == 0) kstar[h*32 + mg*4 + j] = bi;
    }
  }
  __syncthreads();

  float* ob = out + ((size_t)(b*2048 + t0))*256;
  for(int m=0;m<TM;m++){
    const float v = table[((size_t)(i1*32 + kstar[m]))*256 + tid];
    ob[(size_t)m*256 + tid] = v;
  }
}

// ---------------------------------------------------------------------------
extern "C" void kernel_launch(void* const* d_in, const int* in_sizes, int n_in,
                              void* d_out, int out_size, void* d_ws, size_t ws_size,
                              hipStream_t stream){
  const float* x   = (const float*)d_in[0];
  const float* Wg1 = (const float*)d_in[1];
  const float* bg1 = (const float*)d_in[2];
  const float* Wg2 = (const float*)d_in[3];
  const float* bg2 = (const float*)d_in[4];
  const float* Wl1 = (const float*)d_in[5];
  const float* bl1 = (const float*)d_in[6];
  const float* Wl2 = (const float*)d_in[7];
  const float* bl2 = (const float*)d_in[8];
  const float* Wp  = (const float*)d_in[9];
  const float* bp  = (const float*)d_in[10];
  const float* cb1 = (const float*)d_in[11];
  const float* Wtb = (const float*)d_in[12];
  const float* btb = (const float*)d_in[13];
  const float* Wfb = (const float*)d_in[14];
  const float* bfb = (const float*)d_in[15];
  const float* cb2 = (const float*)d_in[16];
  const float* Wf  = (const float*)d_in[17];
  const float* bf  = (const float*)d_in[18];
  float* out = (float*)d_out;

  char* w = (char*)d_ws;
  double* psum   = (double*)w; w += (size_t)16*16*1024*8;   // 2 MB
  double* psumsq = (double*)w; w += (size_t)16*16*1024*8;   // 2 MB
  float*  Wl1T   = (float*)w;  w += (size_t)1024*256*4;     // 1 MB
  float*  Wg1T   = (float*)w;  w += (size_t)1024*256*4;     // 1 MB
  float*  WfT    = (float*)w;  w += (size_t)384*256*4;
  float*  WfbT   = (float*)w;  w += (size_t)64*256*4;
  float*  Wg2T   = (float*)w;  w += (size_t)256*128*4;
  float*  WpT    = (float*)w;  w += (size_t)128*128*4;
  float*  H_all  = (float*)w;  w += (size_t)8*256*32*4;     // 256 KB
  float*  f_all  = (float*)w;  w += (size_t)8*32*4;
  float*  table  = (float*)w;  w += (size_t)256*256*4;      // 256 KB
  int*    idx1   = (int*)w;    w += 64;

  hvq_A<<<488, 256, 0, stream>>>(x, Wl1, Wg1, Wf, Wfb, Wg2, Wp, Wtb, Wl2, bl2, btb, cb2,
                                 psum, psumsq, Wl1T, Wg1T, WfT, WfbT, Wg2T, WpT,
                                 H_all, f_all);
  hvq_B<<<272, 256, 0, stream>>>(psum, psumsq, Wg1T, bg1, Wg2T, bg2, WpT, bp, cb1, cb2,
                                 WfbT, bfb, WfT, bf, idx1, table);
  hvq_main<<<dim3(16,16), 256, 0, stream>>>(x, Wl1T, bl1, H_all, f_all, idx1, table, out);
}

// Round 5
// 637.719 us; speedup vs baseline: 1.0603x; 1.0284x over previous
//
#include <hip/hip_runtime.h>
#include <math.h>

// ---------------------------------------------------------------------------
// HierarchicalVQEncoder forward.
//
// Eval mode: assign = hard one-hot (soft terms cancel), so out[b,t] depends
// ONLY on (idx1[b], idx2[b,t]) -> 8*32=256-row table + gather.
//
// idx2 = argmax_k [ r . H_all[i1][:,k] + f_all[i1][k] ],
//   r = relu(ln(x@Wl1^T+bl1))   (argmax invariant to positive scaling;
//   H,f fold Wl2,Wtb,btb,cb2; computed for ALL 8 i1 to break dependency)
//
// 3-kernel DAG:
//   A: x partial stats | tiled transposes (Wl1,Wg1,Wg2,Wp,Wf,Wfb) | fold H_all
//   B: global encoder -> idx1 (16 blocks) | output table (256 blocks)
//   C: main GEMM + LN + scores + argmax + table gather
//      v6: K-SPLIT 512-thread blocks. Two wave-groups (4 waves each) compute
//      the SAME 128x256 tile over k-halves [0,512)/[512,1024) with the v5
//      8x16 thread tile (0.75 B/FMA) + conflict-free W quads + x swizzle.
//      Waves/SIMD: 1 -> 2 (2048 waves total) so lgkm/vmcnt/barrier stalls
//      hide under the other wave (v5's 190us of exposed stall at 1 wave/SIMD).
//      Partials merged through a swizzled LDS exchange (2x 64-row phases),
//      then group0 runs the verified v5 epilogue; group1 rides barriers.
//
// Precision: big GEMM fp32, all folding math fp64.
// ---------------------------------------------------------------------------

#define TM 128
#define KB 16

typedef __attribute__((address_space(3))) void lds_void_t;
typedef const __attribute__((address_space(1))) void glb_void_t;

__device__ __forceinline__ void async_copy16(const float* g, float* l){
  __builtin_amdgcn_global_load_lds((glb_void_t*)g, (lds_void_t*)l, 16, 0, 0);
}

__device__ __forceinline__ double blk_sum_256(double v, double* red){
  const int tid = threadIdx.x;
  red[tid] = v; __syncthreads();
  #pragma unroll
  for(int s=128; s>0; s>>=1){ if(tid < s) red[tid] += red[tid+s]; __syncthreads(); }
  const double r = red[0]; __syncthreads();
  return r;
}

// ---- tiled 64x64 transpose helper (coalesced in AND out) ----------------
__device__ __forceinline__ void tile_transpose(
    const float* __restrict__ src, float* __restrict__ dst,
    int M, int N, int tile_id, float (*tile)[65]){
  const int tpr = N >> 6;
  const int r0 = (tile_id / tpr) << 6;
  const int c0 = (tile_id % tpr) << 6;
  const int t = threadIdx.x;
  {
    const int i = t >> 4, j4 = (t & 15) << 2;
    #pragma unroll
    for(int q=0;q<4;q++){
      const int row = i + (q<<4);
      const float4 v = *(const float4*)&src[(size_t)(r0+row)*N + c0 + j4];
      tile[row][j4+0]=v.x; tile[row][j4+1]=v.y; tile[row][j4+2]=v.z; tile[row][j4+3]=v.w;
    }
  }
  __syncthreads();
  {
    const int j = t >> 4, i4 = (t & 15) << 2;
    #pragma unroll
    for(int q=0;q<4;q++){
      const int col = j + (q<<4);
      float4 o;
      o.x = tile[i4+0][col]; o.y = tile[i4+1][col];
      o.z = tile[i4+2][col]; o.w = tile[i4+3][col];
      *(float4*)&dst[(size_t)(c0+col)*M + r0 + i4] = o;
    }
  }
}

// ========================= Kernel A (488 blocks) =========================
union SmemA {
  float tile[64][65];
  struct { double Wcs[64][33]; double bcs[64]; double cbd[32][64]; double nrm[32]; } fold;
};

__global__ __launch_bounds__(256) void hvq_A(
    const float* __restrict__ x,
    const float* __restrict__ Wl1, const float* __restrict__ Wg1,
    const float* __restrict__ Wf,  const float* __restrict__ Wfb,
    const float* __restrict__ Wg2, const float* __restrict__ Wp,
    const float* __restrict__ Wtb, const float* __restrict__ Wl2,
    const float* __restrict__ bl2, const float* __restrict__ btb,
    const float* __restrict__ cb2,
    double* __restrict__ psum, double* __restrict__ psumsq,
    float* __restrict__ Wl1T, float* __restrict__ Wg1T,
    float* __restrict__ WfT,  float* __restrict__ WfbT,
    float* __restrict__ Wg2T, float* __restrict__ WpT,
    float* __restrict__ H_all, float* __restrict__ f_all){
  __shared__ SmemA sm;
  const int blk = blockIdx.x;
  const int tid = threadIdx.x;

  if(blk < 256){
    const int tc = blk & 15, b = blk >> 4;
    const int d4 = tid * 4;
    const float* xp = x + ((size_t)(b*2048 + tc*128))*1024 + d4;
    double s0=0,s1=0,s2=0,s3=0, q0=0,q1=0,q2=0,q3=0;
    for(int t=0;t<128;t++){
      const float4 v = *(const float4*)&xp[(size_t)t*1024];
      s0 += v.x; q0 += (double)v.x*v.x;
      s1 += v.y; q1 += (double)v.y*v.y;
      s2 += v.z; q2 += (double)v.z*v.z;
      s3 += v.w; q3 += (double)v.w*v.w;
    }
    const size_t o = ((size_t)(b*16+tc))*1024 + d4;
    psum[o+0]=s0; psum[o+1]=s1; psum[o+2]=s2; psum[o+3]=s3;
    psumsq[o+0]=q0; psumsq[o+1]=q1; psumsq[o+2]=q2; psumsq[o+3]=q3;
  } else if(blk < 320){
    tile_transpose(Wl1, Wl1T, 256, 1024, blk-256, sm.tile);
  } else if(blk < 384){
    tile_transpose(Wg1, Wg1T, 256, 1024, blk-320, sm.tile);
  } else if(blk < 408){
    tile_transpose(Wf,  WfT,  256, 384,  blk-384, sm.tile);
  } else if(blk < 412){
    tile_transpose(Wfb, WfbT, 256, 64,   blk-408, sm.tile);
  } else if(blk < 420){
    tile_transpose(Wg2, Wg2T, 128, 256,  blk-412, sm.tile);
  } else if(blk < 424){
    tile_transpose(Wp,  WpT,  128, 128,  blk-420, sm.tile);
  } else {
    const int fb = blk - 424;
    const int ng = fb & 7;
    const int i1 = fb >> 3;
    const int tn = tid & 31;
    const int kq = tid >> 5;
    const int n  = ng*32 + tn;

    if(tid < 32){
      const float* cr = cb2 + ((size_t)i1*32 + tid)*64;
      double n2 = 0;
      for(int c=0;c<64;c++){ const double v=(double)cr[c]; n2 += v*v; }
      sm.fold.nrm[tid] = fmax(sqrt(n2), 1e-12);
    }
    __syncthreads();
    for(int i=tid;i<2048;i+=256){
      const int k = i >> 6, c = i & 63;
      sm.fold.cbd[k][c] = (double)cb2[((size_t)i1*32+k)*64 + c] / sm.fold.nrm[k];
    }
    {
      double acc[8] = {0,0,0,0,0,0,0,0};
      const float* wt = Wtb + (size_t)(kq*8)*256;
      for(int j=0;j<256;j++){
        const double wl = (double)Wl2[(size_t)j*256 + n];
        #pragma unroll
        for(int cc=0;cc<8;cc++) acc[cc] += (double)wt[cc*256 + j] * wl;
      }
      #pragma unroll
      for(int cc=0;cc<8;cc++) sm.fold.Wcs[kq*8+cc][tn] = acc[cc];
    }
    if(tid < 64){
      const float* wt = Wtb + (size_t)tid*256;
      double a = 0;
      for(int j=0;j<256;j++) a += (double)wt[j]*(double)bl2[j];
      sm.fold.bcs[tid] = a + (double)btb[tid];
    }
    __syncthreads();

    double su = 0;
    for(int c=0;c<64;c++) su += sm.fold.Wcs[c][tn];
    su /= 64.0;
    for(int t=0;t<4;t++){
      const int k = kq*4 + t;
      double acc=0, sk=0;
      for(int c=0;c<64;c++){ const double cc = sm.fold.cbd[k][c]; acc += sm.fold.Wcs[c][tn]*cc; sk += cc; }
      H_all[((size_t)i1*256 + n)*32 + k] = (float)(acc - su*sk);
    }
    if(ng == 0 && tid < 32){
      const int k = tid;
      double acc=0, sk=0, sbc=0;
      for(int c=0;c<64;c++){ const double cc = sm.fold.cbd[k][c]; acc += sm.fold.bcs[c]*cc; sk += cc; sbc += sm.fold.bcs[c]; }
      f_all[i1*32 + k] = (float)(acc - (sbc/64.0)*sk);
    }
  }
}

// ========================= Kernel B (272 blocks) =========================
union SmemB {
  struct { float gin[1024]; float sa[256]; float sb[128]; float sh[128];
           double red[256]; double lg[8]; int i1s; } p2;
  struct { float e[64]; float fused[384]; double red[256]; } p4;
};

__global__ __launch_bounds__(256) void hvq_B(
    const double* __restrict__ psum, const double* __restrict__ psumsq,
    const float* __restrict__ Wg1T, const float* __restrict__ bg1,
    const float* __restrict__ Wg2T, const float* __restrict__ bg2,
    const float* __restrict__ WpT,  const float* __restrict__ bp,
    const float* __restrict__ cb1,  const float* __restrict__ cb2,
    const float* __restrict__ WfbT, const float* __restrict__ bfb,
    const float* __restrict__ WfT,  const float* __restrict__ bf,
    int* __restrict__ idx1_g, float* __restrict__ table){
  __shared__ SmemB sm;
  const int tid = threadIdx.x;

  if(blockIdx.x < 16){
    const int b = blockIdx.x;
    for(int i=tid;i<1024;i+=256){
      double s=0, ss=0;
      for(int tc=0;tc<16;tc++){
        const size_t o = ((size_t)(b*16+tc))*1024 + i;
        s += psum[o]; ss += psumsq[o];
      }
      const double mean = s / 2048.0;
      double var = (ss - s*mean) / 2047.0;
      if(var < 0) var = 0;
      sm.p2.gin[i] = (float)(mean + sqrt(var));
    }
    __syncthreads();

    double z = 0;
    {
      #pragma unroll 8
      for(int k=0;k<1024;k++) z += (double)sm.p2.gin[k] * (double)Wg1T[(size_t)k*256 + tid];
      z += (double)bg1[tid];
    }
    const double mz = blk_sum_256(z, sm.p2.red) / 256.0;
    const double dz = z - mz;
    const double vz = blk_sum_256(dz*dz, sm.p2.red) / 256.0;
    double a = dz / sqrt(vz + 1e-5);
    if(a < 0) a = 0;
    sm.p2.sa[tid] = (float)a;
    __syncthreads();

    if(tid < 128){
      double g = 0;
      #pragma unroll 8
      for(int i=0;i<256;i++) g += (double)sm.p2.sa[i]*(double)Wg2T[(size_t)i*128 + tid];
      sm.p2.sb[tid] = (float)(g + (double)bg2[tid]);
    }
    __syncthreads();

    double h = 0;
    if(tid < 128){
      #pragma unroll 8
      for(int i=0;i<128;i++) h += (double)sm.p2.sb[i]*(double)WpT[(size_t)i*128 + tid];
      h += (double)bp[tid];
    }
    const double mh = blk_sum_256(tid<128 ? h : 0.0, sm.p2.red) / 128.0;
    const double dh = (tid<128) ? (h - mh) : 0.0;
    const double vh = blk_sum_256(dh*dh, sm.p2.red) / 128.0;
    const double h1 = dh / sqrt(vh + 1e-5);
    if(tid < 128) sm.p2.sh[tid] = (float)h1;
    const double nh2 = blk_sum_256(tid<128 ? h1*h1 : 0.0, sm.p2.red);
    const double normh = sqrt(nh2);
    __syncthreads();

    if(tid < 8){
      const float* cr = cb1 + tid*128;
      double dsum=0, n2=0;
      for(int i=0;i<128;i++){ const double c=(double)cr[i]; dsum += (double)sm.p2.sh[i]*c; n2 += c*c; }
      sm.p2.lg[tid] = dsum / (fmax(normh,1e-12) * fmax(sqrt(n2),1e-12));
    }
    __syncthreads();
    if(tid == 0){
      int bi=0; double bv=sm.p2.lg[0];
      for(int j=1;j<8;j++) if(sm.p2.lg[j] > bv){ bv=sm.p2.lg[j]; bi=j; }
      idx1_g[b] = bi;
    }
  } else {
    const int row = blockIdx.x - 16;
    const int i1 = row >> 5, k2 = row & 31;
    const int j = tid;
    if(j < 64) sm.p4.e[j] = cb2[((size_t)i1*32 + k2)*64 + j];
    if(j >= 128 && j < 256) sm.p4.fused[256 + (j-128)] = cb1[i1*128 + (j-128)];
    __syncthreads();

    double t = 0;
    {
      #pragma unroll 8
      for(int c=0;c<64;c++) t += (double)sm.p4.e[c]*(double)WfbT[(size_t)c*256 + j];
      t += (double)bfb[j];
    }
    double m = blk_sum_256(t, sm.p4.red) / 256.0;
    double d = t - m;
    double v = blk_sum_256(d*d, sm.p4.red) / 256.0;
    sm.p4.fused[j] = (float)(d / sqrt(v + 1e-5));
    __syncthreads();

    double o = 0;
    {
      #pragma unroll 8
      for(int i=0;i<384;i++) o += (double)sm.p4.fused[i]*(double)WfT[(size_t)i*256 + j];
      o += (double)bf[j];
    }
    m = blk_sum_256(o, sm.p4.red) / 256.0;
    d = o - m;
    v = blk_sum_256(d*d, sm.p4.red) / 256.0;
    double r = d / sqrt(v + 1e-5);
    if(r < 0) r = 0;
    table[(size_t)row*256 + j] = (float)r;
  }
}

// ========================= Kernel C: main (TM=128, k-split) ==============
// 512 threads = 2 k-groups x (16 tx x 16 ty). Group g covers k in
// [g*512, g*512+512). Thread tile 8 rows x 16 cols (cols q*64+tx*4+c).
// Per group: KB=16 dbuf (W 16KB + x 8KB per buf) at smem + g*2*BUFSZ.
// After the 32-tile K-loop, group1's partials stream through a swizzled
// LDS exchange (64x260, quad ^ (row>>3)&3) in two 64-row phases into
// group0's acc; group0 then runs the (verified) v5 epilogue.
#define WFLOATS (KB*256)            // 4096
#define BUFSZ   (WFLOATS + TM*KB)   // 6144 floats = 24KB
#define XCH_STRIDE 260

__global__ __launch_bounds__(512, 2) void hvq_main(
    const float* __restrict__ x, const float* __restrict__ Wl1T,
    const float* __restrict__ bl1, const float* __restrict__ H_all,
    const float* __restrict__ f_all, const int* __restrict__ idx1,
    const float* __restrict__ table, float* __restrict__ out){
  __shared__ float smem[4*BUFSZ];          // 98304 B
  float* xch = smem;                       // merge buffer, 64x260 fp32
  float* rT  = smem;                       // [n][36] epilogue (after merge)
  int* kstar = (int*)&smem[9216];          // 128 ints (written after merge)

  const int tid = threadIdx.x;
  const int g   = tid >> 8;     // k-half group
  const int gt  = tid & 255;
  const int tx  = gt & 15;      // col quads: q*64 + tx*4
  const int ty  = gt >> 4;      // rows ty*8 .. +7
  const int wg  = gt >> 6;      // wave within group, 0..3
  const int lane = tid & 63;
  const int b  = blockIdx.y;
  const int t0 = blockIdx.x * TM;
  const int i1 = idx1[b];

  float acc[8][16];
  #pragma unroll
  for(int j=0;j<8;j++)
    #pragma unroll
    for(int c=0;c<16;c++) acc[j][c] = 0.f;

  float bn[16];
  #pragma unroll
  for(int q=0;q<4;q++){
    const float4 bv = *(const float4*)&bl1[q*64 + tx*4];
    bn[q*4+0]=bv.x; bn[q*4+1]=bv.y; bn[q*4+2]=bv.z; bn[q*4+3]=bv.w;
  }

  // ---- staging sources (group k-offset g*512) ----
  const float* wsrc0 = Wl1T + (size_t)g*512*256 + wg*1024 + lane*4;
  const int r0 = b*2048 + t0 + wg*32 + (lane>>2);
  const float* xsrc0 = x + (size_t)r0*1024 + g*512
                         + (size_t)(((lane&3) ^ (lane>>5)) * 4);
  const float* xsrc1 = x + (size_t)(r0+16)*1024 + g*512
                         + (size_t)(((lane&3) ^ (2 + (lane>>5))) * 4);

  float* gbase = smem + g*2*BUFSZ;

  auto stage = [&](int kt, float* buf) __attribute__((always_inline)) {
    float* wdst = buf + wg*1024;
    const float* ws = wsrc0 + (size_t)kt*WFLOATS;
    #pragma unroll
    for(int i=0;i<4;i++) async_copy16(ws + i*256, wdst + i*256);
    float* xdst = buf + WFLOATS + wg*512;
    async_copy16(xsrc0 + kt*KB, xdst);
    async_copy16(xsrc1 + kt*KB, xdst + 256);
  };

  stage(0, gbase);

  const int xkey = (ty & 3);           // row>>3 == ty (mod 4) for rows ty*8+j

  for(int kt=0; kt<32; kt++){
    __syncthreads();   // tile kt landed + compute(kt-1) done -> other buf free
    float* cbuf = gbase + (kt&1)*BUFSZ;
    if(kt+1 < 32) stage(kt+1, gbase + ((kt+1)&1)*BUFSZ);

    const float* wsT = cbuf;              // [kk][256]
    const float* xs  = cbuf + WFLOATS;    // [row][16], chunk-swizzled
    #pragma unroll
    for(int kg=0; kg<KB/4; kg++){
      float4 xv[8];
      const int slot = (kg ^ xkey) * 4;
      #pragma unroll
      for(int j=0;j<8;j++) xv[j] = *(const float4*)&xs[(ty*8+j)*16 + slot];
      #pragma unroll
      for(int t=0;t<4;t++){
        const int kk = kg*4 + t;
        const float4 w0 = *(const float4*)&wsT[kk*256 +   0 + tx*4];
        const float4 w1 = *(const float4*)&wsT[kk*256 +  64 + tx*4];
        const float4 w2 = *(const float4*)&wsT[kk*256 + 128 + tx*4];
        const float4 w3 = *(const float4*)&wsT[kk*256 + 192 + tx*4];
        #pragma unroll
        for(int j=0;j<8;j++){
          const float xvj = (&xv[j].x)[t];
          acc[j][ 0] = fmaf(xvj, w0.x, acc[j][ 0]);
          acc[j][ 1] = fmaf(xvj, w0.y, acc[j][ 1]);
          acc[j][ 2] = fmaf(xvj, w0.z, acc[j][ 2]);
          acc[j][ 3] = fmaf(xvj, w0.w, acc[j][ 3]);
          acc[j][ 4] = fmaf(xvj, w1.x, acc[j][ 4]);
          acc[j][ 5] = fmaf(xvj, w1.y, acc[j][ 5]);
          acc[j][ 6] = fmaf(xvj, w1.z, acc[j][ 6]);
          acc[j][ 7] = fmaf(xvj, w1.w, acc[j][ 7]);
          acc[j][ 8] = fmaf(xvj, w2.x, acc[j][ 8]);
          acc[j][ 9] = fmaf(xvj, w2.y, acc[j][ 9]);
          acc[j][10] = fmaf(xvj, w2.z, acc[j][10]);
          acc[j][11] = fmaf(xvj, w2.w, acc[j][11]);
          acc[j][12] = fmaf(xvj, w3.x, acc[j][12]);
          acc[j][13] = fmaf(xvj, w3.y, acc[j][13]);
          acc[j][14] = fmaf(xvj, w3.z, acc[j][14]);
          acc[j][15] = fmaf(xvj, w3.w, acc[j][15]);
        }
      }
    }
  }
  __syncthreads();     // all compute done; LDS free for merge

  // ---- merge: group1 partials -> group0 acc (two 64-row phases) ----
  #pragma unroll
  for(int ph=0; ph<2; ph++){
    const bool mine = (ty>>3) == ph;     // rows ty*8..+7 in [ph*64, ph*64+64)
    if(g==1 && mine){
      #pragma unroll
      for(int j=0;j<8;j++){
        const int row = ty*8 + j, rl = row & 63;
        const int key = (row>>3) & 3;
        #pragma unroll
        for(int q=0;q<4;q++){
          const int qs = (q*16 + tx) ^ key;
          float4 v; v.x=acc[j][q*4+0]; v.y=acc[j][q*4+1];
                    v.z=acc[j][q*4+2]; v.w=acc[j][q*4+3];
          *(float4*)&xch[rl*XCH_STRIDE + qs*4] = v;
        }
      }
    }
    __syncthreads();
    if(g==0 && mine){
      #pragma unroll
      for(int j=0;j<8;j++){
        const int row = ty*8 + j, rl = row & 63;
        const int key = (row>>3) & 3;
        #pragma unroll
        for(int q=0;q<4;q++){
          const int qs = (q*16 + tx) ^ key;
          const float4 v = *(const float4*)&xch[rl*XCH_STRIDE + qs*4];
          acc[j][q*4+0]+=v.x; acc[j][q*4+1]+=v.y;
          acc[j][q*4+2]+=v.z; acc[j][q*4+3]+=v.w;
        }
      }
    }
    __syncthreads();
  }

  // bias + LN(256) per row (reduce across the 16 tx lanes) + ReLU
  // (group1 computes on its partials -- garbage, unused; keeps code uniform)
  #pragma unroll
  for(int j=0;j<8;j++){
    float s = 0.f;
    #pragma unroll
    for(int c=0;c<16;c++){ acc[j][c] += bn[c]; s += acc[j][c]; }
    #pragma unroll
    for(int off=8;off>=1;off>>=1) s += __shfl_xor(s, off);
    const float mean = s * (1.f/256.f);
    float d2 = 0.f;
    #pragma unroll
    for(int c=0;c<16;c++){ const float dv = acc[j][c]-mean; d2 += dv*dv; }
    #pragma unroll
    for(int off=8;off>=1;off>>=1) d2 += __shfl_xor(d2, off);
    const float inv = 1.f / sqrtf(d2*(1.f/256.f) + 1e-5f);
    #pragma unroll
    for(int c=0;c<16;c++) acc[j][c] = fmaxf((acc[j][c]-mean)*inv, 0.f);
  }

  // scores in four 32-row quarters (rT = 32 rows x 256 n, stride 36)
  const int k = tid & 31, mg = (tid >> 5) & 7;   // mg 0..7 (both groups alias)
  const float* Hb = H_all + (size_t)i1*256*32 + k;
  const float fk = f_all[i1*32 + k];
  const int quarter = ty >> 2;             // which quarter owns this thread's rows
  const int mm_base = (ty & 3)*8;

  for(int h=0; h<4; h++){
    __syncthreads();                       // prior phase reads done
    if(g==0 && quarter == h){
      #pragma unroll
      for(int j=0;j<8;j++){
        #pragma unroll
        for(int q=0;q<4;q++){
          #pragma unroll
          for(int c=0;c<4;c++){
            rT[(q*64 + tx*4 + c)*36 + mm_base + j] = acc[j][q*4+c];
          }
        }
      }
    }
    __syncthreads();

    float s0=fk, s1=fk, s2=fk, s3=fk;
    #pragma unroll 4
    for(int n=0;n<256;n++){
      const float4 rm = *(const float4*)&rT[n*36 + mg*4];
      const float hv = Hb[(size_t)n*32];
      s0 = fmaf(rm.x, hv, s0);
      s1 = fmaf(rm.y, hv, s1);
      s2 = fmaf(rm.z, hv, s2);
      s3 = fmaf(rm.w, hv, s3);
    }
    float scv[4] = {s0, s1, s2, s3};
    #pragma unroll
    for(int j=0;j<4;j++){
      float best = scv[j]; int bi = k;
      #pragma unroll
      for(int off=16;off>=1;off>>=1){
        const float ov = __shfl_xor(best, off);
        const int   oi = __shfl_xor(bi, off);
        if(ov > best || (ov == best && oi < bi)){ best = ov; bi = oi; }
      }
      if(k == 0 && tid < 256) kstar[h*32 + mg*4 + j] = bi;
    }
  }
  __syncthreads();

  // final gather: group g covers rows [g*64, g*64+64), col = gt
  float* ob = out + ((size_t)(b*2048 + t0))*256;
  for(int m=g*64; m<g*64+64; m++){
    const float v = table[((size_t)(i1*32 + kstar[m]))*256 + gt];
    ob[(size_t)m*256 + gt] = v;
  }
}

// ---------------------------------------------------------------------------
extern "C" void kernel_launch(void* const* d_in, const int* in_sizes, int n_in,
                              void* d_out, int out_size, void* d_ws, size_t ws_size,
                              hipStream_t stream){
  const float* x   = (const float*)d_in[0];
  const float* Wg1 = (const float*)d_in[1];
  const float* bg1 = (const float*)d_in[2];
  const float* Wg2 = (const float*)d_in[3];
  const float* bg2 = (const float*)d_in[4];
  const float* Wl1 = (const float*)d_in[5];
  const float* bl1 = (const float*)d_in[6];
  const float* Wl2 = (const float*)d_in[7];
  const float* bl2 = (const float*)d_in[8];
  const float* Wp  = (const float*)d_in[9];
  const float* bp  = (const float*)d_in[10];
  const float* cb1 = (const float*)d_in[11];
  const float* Wtb = (const float*)d_in[12];
  const float* btb = (const float*)d_in[13];
  const float* Wfb = (const float*)d_in[14];
  const float* bfb = (const float*)d_in[15];
  const float* cb2 = (const float*)d_in[16];
  const float* Wf  = (const float*)d_in[17];
  const float* bf  = (const float*)d_in[18];
  float* out = (float*)d_out;

  char* w = (char*)d_ws;
  double* psum   = (double*)w; w += (size_t)16*16*1024*8;   // 2 MB
  double* psumsq = (double*)w; w += (size_t)16*16*1024*8;   // 2 MB
  float*  Wl1T   = (float*)w;  w += (size_t)1024*256*4;     // 1 MB
  float*  Wg1T   = (float*)w;  w += (size_t)1024*256*4;     // 1 MB
  float*  WfT    = (float*)w;  w += (size_t)384*256*4;
  float*  WfbT   = (float*)w;  w += (size_t)64*256*4;
  float*  Wg2T   = (float*)w;  w += (size_t)256*128*4;
  float*  WpT    = (float*)w;  w += (size_t)128*128*4;
  float*  H_all  = (float*)w;  w += (size_t)8*256*32*4;     // 256 KB
  float*  f_all  = (float*)w;  w += (size_t)8*32*4;
  float*  table  = (float*)w;  w += (size_t)256*256*4;      // 256 KB
  int*    idx1   = (int*)w;    w += 64;

  hvq_A<<<488, 256, 0, stream>>>(x, Wl1, Wg1, Wf, Wfb, Wg2, Wp, Wtb, Wl2, bl2, btb, cb2,
                                 psum, psumsq, Wl1T, Wg1T, WfT, WfbT, Wg2T, WpT,
                                 H_all, f_all);
  hvq_B<<<272, 256, 0, stream>>>(psum, psumsq, Wg1T, bg1, Wg2T, bg2, WpT, bp, cb1, cb2,
                                 WfbT, bfb, WfT, bf, idx1, table);
  hvq_main<<<dim3(16,16), 512, 0, stream>>>(x, Wl1T, bl1, H_all, f_all, idx1, table, out);
}

// Round 6
// 606.483 us; speedup vs baseline: 1.1149x; 1.0515x over previous
//
#include <hip/hip_runtime.h>
#include <math.h>

// ---------------------------------------------------------------------------
// HierarchicalVQEncoder forward.
//
// Eval mode: assign = hard one-hot (soft terms cancel), so out[b,t] depends
// ONLY on (idx1[b], idx2[b,t]) -> 8*32=256-row table + gather.
//
// idx2 = argmax_k [ r . H_all[i1][:,k] + f_all[i1][k] ],
//   r = relu(ln(x@Wl1^T+bl1))   (argmax invariant to positive scaling;
//   H,f fold Wl2,Wtb,btb,cb2; computed for ALL 8 i1 to break dependency)
//
// 3-kernel DAG:
//   A: x partial stats | tiled transposes (Wl1,Wg1,Wg2,Wp,Wf,Wfb) | fold H_all
//   B: global encoder -> idx1 (16 blocks) | output table (256 blocks)
//   C: main GEMM + LN + scores + argmax + table gather
//      v7: v2's proven single-buffer KB=32 structure at TM=32 ->
//      grid 1024 blocks = 4 blocks/CU = 4 waves/SIMD (v2's grid of 512
//      capped occupancy at 2/CU; that, not LDS bandwidth, was the limit:
//      W reads are 2-way-dup broadcasts, x reads 2-address broadcasts).
//      36.1KB LDS/block (4 fit in 160KB); 4x8 thread tile, ~85 VGPR, no
//      spills (v6's 512-thread blocks halved the register budget and spilled
//      acc to scratch: WRITE_SIZE 32->89MB).
//
// Precision: big GEMM fp32, all folding math fp64.
// ---------------------------------------------------------------------------

#define TM 32
#define KB 32

typedef __attribute__((address_space(3))) void lds_void_t;
typedef const __attribute__((address_space(1))) void glb_void_t;

__device__ __forceinline__ void async_copy16(const float* g, float* l){
  __builtin_amdgcn_global_load_lds((glb_void_t*)g, (lds_void_t*)l, 16, 0, 0);
}

__device__ __forceinline__ double blk_sum_256(double v, double* red){
  const int tid = threadIdx.x;
  red[tid] = v; __syncthreads();
  #pragma unroll
  for(int s=128; s>0; s>>=1){ if(tid < s) red[tid] += red[tid+s]; __syncthreads(); }
  const double r = red[0]; __syncthreads();
  return r;
}

// ---- tiled 64x64 transpose helper (coalesced in AND out) ----------------
__device__ __forceinline__ void tile_transpose(
    const float* __restrict__ src, float* __restrict__ dst,
    int M, int N, int tile_id, float (*tile)[65]){
  const int tpr = N >> 6;
  const int r0 = (tile_id / tpr) << 6;
  const int c0 = (tile_id % tpr) << 6;
  const int t = threadIdx.x;
  {
    const int i = t >> 4, j4 = (t & 15) << 2;
    #pragma unroll
    for(int q=0;q<4;q++){
      const int row = i + (q<<4);
      const float4 v = *(const float4*)&src[(size_t)(r0+row)*N + c0 + j4];
      tile[row][j4+0]=v.x; tile[row][j4+1]=v.y; tile[row][j4+2]=v.z; tile[row][j4+3]=v.w;
    }
  }
  __syncthreads();
  {
    const int j = t >> 4, i4 = (t & 15) << 2;
    #pragma unroll
    for(int q=0;q<4;q++){
      const int col = j + (q<<4);
      float4 o;
      o.x = tile[i4+0][col]; o.y = tile[i4+1][col];
      o.z = tile[i4+2][col]; o.w = tile[i4+3][col];
      *(float4*)&dst[(size_t)(c0+col)*M + r0 + i4] = o;
    }
  }
}

// ========================= Kernel A (488 blocks) =========================
union SmemA {
  float tile[64][65];
  struct { double Wcs[64][33]; double bcs[64]; double cbd[32][64]; double nrm[32]; } fold;
};

__global__ __launch_bounds__(256) void hvq_A(
    const float* __restrict__ x,
    const float* __restrict__ Wl1, const float* __restrict__ Wg1,
    const float* __restrict__ Wf,  const float* __restrict__ Wfb,
    const float* __restrict__ Wg2, const float* __restrict__ Wp,
    const float* __restrict__ Wtb, const float* __restrict__ Wl2,
    const float* __restrict__ bl2, const float* __restrict__ btb,
    const float* __restrict__ cb2,
    double* __restrict__ psum, double* __restrict__ psumsq,
    float* __restrict__ Wl1T, float* __restrict__ Wg1T,
    float* __restrict__ WfT,  float* __restrict__ WfbT,
    float* __restrict__ Wg2T, float* __restrict__ WpT,
    float* __restrict__ H_all, float* __restrict__ f_all){
  __shared__ SmemA sm;
  const int blk = blockIdx.x;
  const int tid = threadIdx.x;

  if(blk < 256){
    const int tc = blk & 15, b = blk >> 4;
    const int d4 = tid * 4;
    const float* xp = x + ((size_t)(b*2048 + tc*128))*1024 + d4;
    double s0=0,s1=0,s2=0,s3=0, q0=0,q1=0,q2=0,q3=0;
    for(int t=0;t<128;t++){
      const float4 v = *(const float4*)&xp[(size_t)t*1024];
      s0 += v.x; q0 += (double)v.x*v.x;
      s1 += v.y; q1 += (double)v.y*v.y;
      s2 += v.z; q2 += (double)v.z*v.z;
      s3 += v.w; q3 += (double)v.w*v.w;
    }
    const size_t o = ((size_t)(b*16+tc))*1024 + d4;
    psum[o+0]=s0; psum[o+1]=s1; psum[o+2]=s2; psum[o+3]=s3;
    psumsq[o+0]=q0; psumsq[o+1]=q1; psumsq[o+2]=q2; psumsq[o+3]=q3;
  } else if(blk < 320){
    tile_transpose(Wl1, Wl1T, 256, 1024, blk-256, sm.tile);
  } else if(blk < 384){
    tile_transpose(Wg1, Wg1T, 256, 1024, blk-320, sm.tile);
  } else if(blk < 408){
    tile_transpose(Wf,  WfT,  256, 384,  blk-384, sm.tile);
  } else if(blk < 412){
    tile_transpose(Wfb, WfbT, 256, 64,   blk-408, sm.tile);
  } else if(blk < 420){
    tile_transpose(Wg2, Wg2T, 128, 256,  blk-412, sm.tile);
  } else if(blk < 424){
    tile_transpose(Wp,  WpT,  128, 128,  blk-420, sm.tile);
  } else {
    const int fb = blk - 424;
    const int ng = fb & 7;
    const int i1 = fb >> 3;
    const int tn = tid & 31;
    const int kq = tid >> 5;
    const int n  = ng*32 + tn;

    if(tid < 32){
      const float* cr = cb2 + ((size_t)i1*32 + tid)*64;
      double n2 = 0;
      for(int c=0;c<64;c++){ const double v=(double)cr[c]; n2 += v*v; }
      sm.fold.nrm[tid] = fmax(sqrt(n2), 1e-12);
    }
    __syncthreads();
    for(int i=tid;i<2048;i+=256){
      const int k = i >> 6, c = i & 63;
      sm.fold.cbd[k][c] = (double)cb2[((size_t)i1*32+k)*64 + c] / sm.fold.nrm[k];
    }
    {
      double acc[8] = {0,0,0,0,0,0,0,0};
      const float* wt = Wtb + (size_t)(kq*8)*256;
      for(int j=0;j<256;j++){
        const double wl = (double)Wl2[(size_t)j*256 + n];
        #pragma unroll
        for(int cc=0;cc<8;cc++) acc[cc] += (double)wt[cc*256 + j] * wl;
      }
      #pragma unroll
      for(int cc=0;cc<8;cc++) sm.fold.Wcs[kq*8+cc][tn] = acc[cc];
    }
    if(tid < 64){
      const float* wt = Wtb + (size_t)tid*256;
      double a = 0;
      for(int j=0;j<256;j++) a += (double)wt[j]*(double)bl2[j];
      sm.fold.bcs[tid] = a + (double)btb[tid];
    }
    __syncthreads();

    double su = 0;
    for(int c=0;c<64;c++) su += sm.fold.Wcs[c][tn];
    su /= 64.0;
    for(int t=0;t<4;t++){
      const int k = kq*4 + t;
      double acc=0, sk=0;
      for(int c=0;c<64;c++){ const double cc = sm.fold.cbd[k][c]; acc += sm.fold.Wcs[c][tn]*cc; sk += cc; }
      H_all[((size_t)i1*256 + n)*32 + k] = (float)(acc - su*sk);
    }
    if(ng == 0 && tid < 32){
      const int k = tid;
      double acc=0, sk=0, sbc=0;
      for(int c=0;c<64;c++){ const double cc = sm.fold.cbd[k][c]; acc += sm.fold.bcs[c]*cc; sk += cc; sbc += sm.fold.bcs[c]; }
      f_all[i1*32 + k] = (float)(acc - (sbc/64.0)*sk);
    }
  }
}

// ========================= Kernel B (272 blocks) =========================
union SmemB {
  struct { float gin[1024]; float sa[256]; float sb[128]; float sh[128];
           double red[256]; double lg[8]; int i1s; } p2;
  struct { float e[64]; float fused[384]; double red[256]; } p4;
};

__global__ __launch_bounds__(256) void hvq_B(
    const double* __restrict__ psum, const double* __restrict__ psumsq,
    const float* __restrict__ Wg1T, const float* __restrict__ bg1,
    const float* __restrict__ Wg2T, const float* __restrict__ bg2,
    const float* __restrict__ WpT,  const float* __restrict__ bp,
    const float* __restrict__ cb1,  const float* __restrict__ cb2,
    const float* __restrict__ WfbT, const float* __restrict__ bfb,
    const float* __restrict__ WfT,  const float* __restrict__ bf,
    int* __restrict__ idx1_g, float* __restrict__ table){
  __shared__ SmemB sm;
  const int tid = threadIdx.x;

  if(blockIdx.x < 16){
    const int b = blockIdx.x;
    for(int i=tid;i<1024;i+=256){
      double s=0, ss=0;
      for(int tc=0;tc<16;tc++){
        const size_t o = ((size_t)(b*16+tc))*1024 + i;
        s += psum[o]; ss += psumsq[o];
      }
      const double mean = s / 2048.0;
      double var = (ss - s*mean) / 2047.0;
      if(var < 0) var = 0;
      sm.p2.gin[i] = (float)(mean + sqrt(var));
    }
    __syncthreads();

    double z = 0;
    {
      #pragma unroll 8
      for(int k=0;k<1024;k++) z += (double)sm.p2.gin[k] * (double)Wg1T[(size_t)k*256 + tid];
      z += (double)bg1[tid];
    }
    const double mz = blk_sum_256(z, sm.p2.red) / 256.0;
    const double dz = z - mz;
    const double vz = blk_sum_256(dz*dz, sm.p2.red) / 256.0;
    double a = dz / sqrt(vz + 1e-5);
    if(a < 0) a = 0;
    sm.p2.sa[tid] = (float)a;
    __syncthreads();

    if(tid < 128){
      double g = 0;
      #pragma unroll 8
      for(int i=0;i<256;i++) g += (double)sm.p2.sa[i]*(double)Wg2T[(size_t)i*128 + tid];
      sm.p2.sb[tid] = (float)(g + (double)bg2[tid]);
    }
    __syncthreads();

    double h = 0;
    if(tid < 128){
      #pragma unroll 8
      for(int i=0;i<128;i++) h += (double)sm.p2.sb[i]*(double)WpT[(size_t)i*128 + tid];
      h += (double)bp[tid];
    }
    const double mh = blk_sum_256(tid<128 ? h : 0.0, sm.p2.red) / 128.0;
    const double dh = (tid<128) ? (h - mh) : 0.0;
    const double vh = blk_sum_256(dh*dh, sm.p2.red) / 128.0;
    const double h1 = dh / sqrt(vh + 1e-5);
    if(tid < 128) sm.p2.sh[tid] = (float)h1;
    const double nh2 = blk_sum_256(tid<128 ? h1*h1 : 0.0, sm.p2.red);
    const double normh = sqrt(nh2);
    __syncthreads();

    if(tid < 8){
      const float* cr = cb1 + tid*128;
      double dsum=0, n2=0;
      for(int i=0;i<128;i++){ const double c=(double)cr[i]; dsum += (double)sm.p2.sh[i]*c; n2 += c*c; }
      sm.p2.lg[tid] = dsum / (fmax(normh,1e-12) * fmax(sqrt(n2),1e-12));
    }
    __syncthreads();
    if(tid == 0){
      int bi=0; double bv=sm.p2.lg[0];
      for(int j=1;j<8;j++) if(sm.p2.lg[j] > bv){ bv=sm.p2.lg[j]; bi=j; }
      idx1_g[b] = bi;
    }
  } else {
    const int row = blockIdx.x - 16;
    const int i1 = row >> 5, k2 = row & 31;
    const int j = tid;
    if(j < 64) sm.p4.e[j] = cb2[((size_t)i1*32 + k2)*64 + j];
    if(j >= 128 && j < 256) sm.p4.fused[256 + (j-128)] = cb1[i1*128 + (j-128)];
    __syncthreads();

    double t = 0;
    {
      #pragma unroll 8
      for(int c=0;c<64;c++) t += (double)sm.p4.e[c]*(double)WfbT[(size_t)c*256 + j];
      t += (double)bfb[j];
    }
    double m = blk_sum_256(t, sm.p4.red) / 256.0;
    double d = t - m;
    double v = blk_sum_256(d*d, sm.p4.red) / 256.0;
    sm.p4.fused[j] = (float)(d / sqrt(v + 1e-5));
    __syncthreads();

    double o = 0;
    {
      #pragma unroll 8
      for(int i=0;i<384;i++) o += (double)sm.p4.fused[i]*(double)WfT[(size_t)i*256 + j];
      o += (double)bf[j];
    }
    m = blk_sum_256(o, sm.p4.red) / 256.0;
    d = o - m;
    v = blk_sum_256(d*d, sm.p4.red) / 256.0;
    double r = d / sqrt(v + 1e-5);
    if(r < 0) r = 0;
    table[(size_t)row*256 + j] = (float)r;
  }
}

// ========================= Kernel C: main (TM=32) ========================
// v7: 256 threads = 32 tx x 8 ty; thread tile 4 rows x 8 cols
// (rows ty*4+j, cols tx*4+c and 128+tx*4+c -- v2's proven pattern).
// Single 36.1KB LDS buffer (W [32][256] 32KB + x [32][32] 4KB), KB=32,
// stage -> barrier -> compute -> barrier per tile. Grid 64x16 = 1024
// blocks = 4 blocks/CU = 4 waves/SIMD: stalls hide across blocks.
// Epilogue: one 32-row rT phase + scores + argmax + table gather.
__global__ __launch_bounds__(256) void hvq_main(
    const float* __restrict__ x, const float* __restrict__ Wl1T,
    const float* __restrict__ bl1, const float* __restrict__ H_all,
    const float* __restrict__ f_all, const int* __restrict__ idx1,
    const float* __restrict__ table, float* __restrict__ out){
  __shared__ float smem[KB*256 + TM*KB + 32];   // 8192 + 1024 + 32 = 36992B
  float* wsT = smem;                // [kk][256]
  float* xs  = smem + KB*256;       // [m][kk]
  float* rT  = smem;                // [n][36] epilogue alias, 9216 floats
  int* kstar = (int*)&smem[KB*256 + TM*KB];     // 32 ints

  const int tid = threadIdx.x;
  const int tx = tid & 31, ty = tid >> 5;   // tx: col quads, ty: 4-row group
  const int wave = tid >> 6;
  const int lane = tid & 63;
  const int b  = blockIdx.y;
  const int t0 = blockIdx.x * TM;
  const int i1 = idx1[b];

  float acc[4][8];
  #pragma unroll
  for(int j=0;j<4;j++)
    #pragma unroll
    for(int c=0;c<8;c++) acc[j][c] = 0.f;

  float bn[8];
  #pragma unroll
  for(int c=0;c<4;c++){ bn[c] = bl1[tx*4+c]; bn[c+4] = bl1[128 + tx*4 + c]; }

  // staging: W 8 insts/wave (wave covers floats [wave*2048,+2048));
  //          x 1 inst/thread: row tid>>3, 16B chunk tid&7 (LDS linear).
  const float* xsrc = x + ((size_t)(b*2048 + t0 + (tid>>3)))*1024 + (tid&7)*4;
  float* xdst = xs + tid*4;
  float* wdst = wsT + wave*2048;

  for(int kt=0; kt<1024/KB; kt++){
    const float* wsrc = Wl1T + (size_t)kt*(KB*256) + wave*2048 + lane*4;
    #pragma unroll
    for(int i=0;i<8;i++) async_copy16(wsrc + i*256, wdst + i*256);
    async_copy16(xsrc + kt*KB, xdst);
    __syncthreads();

    #pragma unroll
    for(int kg=0; kg<KB/4; kg++){
      float4 xv[4];
      #pragma unroll
      for(int j=0;j<4;j++) xv[j] = *(const float4*)&xs[(ty*4+j)*KB + kg*4];
      #pragma unroll
      for(int t=0;t<4;t++){
        const int kk = kg*4 + t;
        const float4 w0 = *(const float4*)&wsT[kk*256 + tx*4];
        const float4 w1 = *(const float4*)&wsT[kk*256 + 128 + tx*4];
        #pragma unroll
        for(int j=0;j<4;j++){
          const float xvj = (&xv[j].x)[t];
          acc[j][0] = fmaf(xvj, w0.x, acc[j][0]);
          acc[j][1] = fmaf(xvj, w0.y, acc[j][1]);
          acc[j][2] = fmaf(xvj, w0.z, acc[j][2]);
          acc[j][3] = fmaf(xvj, w0.w, acc[j][3]);
          acc[j][4] = fmaf(xvj, w1.x, acc[j][4]);
          acc[j][5] = fmaf(xvj, w1.y, acc[j][5]);
          acc[j][6] = fmaf(xvj, w1.z, acc[j][6]);
          acc[j][7] = fmaf(xvj, w1.w, acc[j][7]);
        }
      }
    }
    __syncthreads();
  }

  // bias + LN(256) per row (reduce across 32 tx lanes) + ReLU, in registers
  #pragma unroll
  for(int j=0;j<4;j++){
    float s = 0.f;
    #pragma unroll
    for(int c=0;c<8;c++){ acc[j][c] += bn[c]; s += acc[j][c]; }
    #pragma unroll
    for(int off=16;off>=1;off>>=1) s += __shfl_xor(s, off);
    const float mean = s * (1.f/256.f);
    float d2 = 0.f;
    #pragma unroll
    for(int c=0;c<8;c++){ const float dv = acc[j][c]-mean; d2 += dv*dv; }
    #pragma unroll
    for(int off=16;off>=1;off>>=1) d2 += __shfl_xor(d2, off);
    const float inv = 1.f / sqrtf(d2*(1.f/256.f) + 1e-5f);
    #pragma unroll
    for(int c=0;c<8;c++) acc[j][c] = fmaxf((acc[j][c]-mean)*inv, 0.f);
  }

  // single rT phase: 32 rows x 256 n (stride 36), then scores + argmax
  #pragma unroll
  for(int j=0;j<4;j++){
    #pragma unroll
    for(int c=0;c<8;c++){
      const int n = (c < 4) ? (tx*4 + c) : (128 + tx*4 + (c-4));
      rT[n*36 + ty*4 + j] = acc[j][c];
    }
  }
  __syncthreads();

  const int k = tid & 31, mg = tid >> 5;   // mg 0..7 -> rows mg*4..+3
  const float* Hb = H_all + (size_t)i1*256*32 + k;
  const float fk = f_all[i1*32 + k];

  float s0=fk, s1=fk, s2=fk, s3=fk;
  #pragma unroll 4
  for(int n=0;n<256;n++){
    const float4 rm = *(const float4*)&rT[n*36 + mg*4];
    const float hv = Hb[(size_t)n*32];
    s0 = fmaf(rm.x, hv, s0);
    s1 = fmaf(rm.y, hv, s1);
    s2 = fmaf(rm.z, hv, s2);
    s3 = fmaf(rm.w, hv, s3);
  }
  float scv[4] = {s0, s1, s2, s3};
  #pragma unroll
  for(int j=0;j<4;j++){
    float best = scv[j]; int bi = k;
    #pragma unroll
    for(int off=16;off>=1;off>>=1){
      const float ov = __shfl_xor(best, off);
      const int   oi = __shfl_xor(bi, off);
      if(ov > best || (ov == best && oi < bi)){ best = ov; bi = oi; }
    }
    if(k == 0) kstar[mg*4 + j] = bi;
  }
  __syncthreads();

  float* ob = out + ((size_t)(b*2048 + t0))*256;
  for(int m=0;m<TM;m++){
    const float v = table[((size_t)(i1*32 + kstar[m]))*256 + tid];
    ob[(size_t)m*256 + tid] = v;
  }
}

// ---------------------------------------------------------------------------
extern "C" void kernel_launch(void* const* d_in, const int* in_sizes, int n_in,
                              void* d_out, int out_size, void* d_ws, size_t ws_size,
                              hipStream_t stream){
  const float* x   = (const float*)d_in[0];
  const float* Wg1 = (const float*)d_in[1];
  const float* bg1 = (const float*)d_in[2];
  const float* Wg2 = (const float*)d_in[3];
  const float* bg2 = (const float*)d_in[4];
  const float* Wl1 = (const float*)d_in[5];
  const float* bl1 = (const float*)d_in[6];
  const float* Wl2 = (const float*)d_in[7];
  const float* bl2 = (const float*)d_in[8];
  const float* Wp  = (const float*)d_in[9];
  const float* bp  = (const float*)d_in[10];
  const float* cb1 = (const float*)d_in[11];
  const float* Wtb = (const float*)d_in[12];
  const float* btb = (const float*)d_in[13];
  const float* Wfb = (const float*)d_in[14];
  const float* bfb = (const float*)d_in[15];
  const float* cb2 = (const float*)d_in[16];
  const float* Wf  = (const float*)d_in[17];
  const float* bf  = (const float*)d_in[18];
  float* out = (float*)d_out;

  char* w = (char*)d_ws;
  double* psum   = (double*)w; w += (size_t)16*16*1024*8;   // 2 MB
  double* psumsq = (double*)w; w += (size_t)16*16*1024*8;   // 2 MB
  float*  Wl1T   = (float*)w;  w += (size_t)1024*256*4;     // 1 MB
  float*  Wg1T   = (float*)w;  w += (size_t)1024*256*4;     // 1 MB
  float*  WfT    = (float*)w;  w += (size_t)384*256*4;
  float*  WfbT   = (float*)w;  w += (size_t)64*256*4;
  float*  Wg2T   = (float*)w;  w += (size_t)256*128*4;
  float*  WpT    = (float*)w;  w += (size_t)128*128*4;
  float*  H_all  = (float*)w;  w += (size_t)8*256*32*4;     // 256 KB
  float*  f_all  = (float*)w;  w += (size_t)8*32*4;
  float*  table  = (float*)w;  w += (size_t)256*256*4;      // 256 KB
  int*    idx1   = (int*)w;    w += 64;

  hvq_A<<<488, 256, 0, stream>>>(x, Wl1, Wg1, Wf, Wfb, Wg2, Wp, Wtb, Wl2, bl2, btb, cb2,
                                 psum, psumsq, Wl1T, Wg1T, WfT, WfbT, Wg2T, WpT,
                                 H_all, f_all);
  hvq_B<<<272, 256, 0, stream>>>(psum, psumsq, Wg1T, bg1, Wg2T, bg2, WpT, bp, cb1, cb2,
                                 WfbT, bfb, WfT, bf, idx1, table);
  hvq_main<<<dim3(64,16), 256, 0, stream>>>(x, Wl1T, bl1, H_all, f_all, idx1, table, out);
}